// Round 10
// baseline (471.704 us; speedup 1.0000x reference)
//
#include <hip/hip_runtime.h>
#include <math.h>
#include <stdint.h>

typedef unsigned short u16;
typedef unsigned int u32;
typedef __attribute__((ext_vector_type(8))) short short8;
typedef __attribute__((ext_vector_type(4))) float f32x4;

#define MFMA16(a, b, c) __builtin_amdgcn_mfma_f32_16x16x32_bf16(a, b, c, 0, 0, 0)

__device__ __forceinline__ u16 f2bf(float f) {
  union { float f; u32 u; } v; v.f = f;
  return (u16)((v.u + 0x7FFFu + ((v.u >> 16) & 1u)) >> 16);
}
__device__ __forceinline__ float bf2f(u16 h) {
  union { u32 u; float f; } v; v.u = ((u32)h) << 16; return v.f;
}
__device__ __forceinline__ float bflo(u32 p) {
  union { u32 u; float f; } v; v.u = p << 16; return v.f;
}
__device__ __forceinline__ float bfhi(u32 p) {
  union { u32 u; float f; } v; v.u = p & 0xffff0000u; return v.f;
}
__device__ __forceinline__ float sigm(float x) { return 1.f / (1.f + expf(-x)); }

// ---------------- x -> bf16 ----------------
__global__ void k_cvt_x(const float* __restrict__ x, u16* __restrict__ xb) {
  int i = (blockIdx.x * 256 + threadIdx.x) * 8;
  float4 a = *(const float4*)(x + i);
  float4 b = *(const float4*)(x + i + 4);
  uint4 p;
  p.x = (u32)f2bf(a.x) | ((u32)f2bf(a.y) << 16);
  p.y = (u32)f2bf(a.z) | ((u32)f2bf(a.w) << 16);
  p.z = (u32)f2bf(b.x) | ((u32)f2bf(b.y) << 16);
  p.w = (u32)f2bf(b.z) | ((u32)f2bf(b.w) << 16);
  *(uint4*)(xb + i) = p;
}

// ---------------- 4x W transpose: [K][N] f32 -> [N][K] bf16 ----------------
__global__ void k_tconv4(const float* __restrict__ W0, const float* __restrict__ W1,
                         const float* __restrict__ W2, const float* __restrict__ W3,
                         u16* __restrict__ Wt) {
  __shared__ float tile[32][33];
  int z = blockIdx.z;
  const float* W = (z == 0) ? W0 : (z == 1) ? W1 : (z == 2) ? W2 : W3;
  u16* dst = Wt + (size_t)z * 2048 * 2048;
  int n0 = blockIdx.x * 32, k0 = blockIdx.y * 32;
  int tc = threadIdx.x & 31, tr = threadIdx.x >> 5;
  #pragma unroll
  for (int p = 0; p < 4; ++p) {
    int k = k0 + p * 8 + tr;
    tile[p * 8 + tr][tc] = W[(size_t)k * 2048 + n0 + tc];
  }
  __syncthreads();
  #pragma unroll
  for (int p = 0; p < 4; ++p) {
    int n = n0 + p * 8 + tr;
    dst[(size_t)n * 2048 + k0 + tc] = f2bf(tile[tc][p * 8 + tr]);
  }
}

__global__ void k_tconv(const float* __restrict__ W, u16* __restrict__ Wt) {
  __shared__ float tile[32][33];
  int n0 = blockIdx.x * 32, k0 = blockIdx.y * 32;
  int tc = threadIdx.x & 31, tr = threadIdx.x >> 5;
  #pragma unroll
  for (int p = 0; p < 4; ++p) {
    int k = k0 + p * 8 + tr;
    tile[p * 8 + tr][tc] = W[(size_t)k * 2048 + n0 + tc];
  }
  __syncthreads();
  #pragma unroll
  for (int p = 0; p < 4; ++p) {
    int n = n0 + p * 8 + tr;
    Wt[(size_t)n * 2048 + k0 + tc] = f2bf(tile[tc][p * 8 + tr]);
  }
}

// ---------------- alpha/beta GEMV, LDS-tiled f32 ----------------
__global__ __launch_bounds__(256)
void k_ab(const float* __restrict__ x, const float* __restrict__ Wa,
          const float* __restrict__ ba, const float* __restrict__ Wb,
          const float* __restrict__ bb, float* __restrict__ ab2) {
  __shared__ float Wl[128 * 32];
  __shared__ float xl[8][128];
  const int t = threadIdx.x;
  const int lr = t >> 5, c = t & 31;
  const int r0 = blockIdx.x * 8;
  const int ch = c & 15;
  float acc = 0.f;
  for (int kt = 0; kt < 16; ++kt) {
    #pragma unroll
    for (int i = 0; i < 16; ++i) {
      int idx = i * 256 + t;
      int kk = idx >> 5, cc = idx & 31;
      const float* Ws = (cc < 16) ? Wa : Wb;
      Wl[kk * 32 + cc] = Ws[(kt * 128 + kk) * 16 + (cc & 15)];
    }
    #pragma unroll
    for (int i = 0; i < 4; ++i) {
      int idx = i * 256 + t;
      int rr = idx >> 7, kk = idx & 127;
      xl[rr][kk] = x[(size_t)(r0 + rr) * 2048 + kt * 128 + kk];
    }
    __syncthreads();
    #pragma unroll
    for (int kk = 0; kk < 128; kk += 4) {
      float2 x01 = *(const float2*)&xl[lr][kk];
      float2 x23 = *(const float2*)&xl[lr][kk + 2];
      acc += x01.x * Wl[(kk + 0) * 32 + c] + x01.y * Wl[(kk + 1) * 32 + c]
           + x23.x * Wl[(kk + 2) * 32 + c] + x23.y * Wl[(kk + 3) * 32 + c];
    }
    __syncthreads();
  }
  acc += (c < 16) ? ba[ch] : bb[ch];
  float sg = sigm(acc);
  int rowi = r0 + lr;
  int b = rowi >> 11, s = rowi & 2047;
  size_t base = ((size_t)(b * 16 + ch) * 2048 + s) * 2;
  if (c < 16) ab2[base + 0] = sg;
  else        ab2[base + 1] = sg;
}

__device__ __forceinline__ void gld_lds16(const u16* g, u16* l) {
  __builtin_amdgcn_global_load_lds((const __attribute__((address_space(1))) void*)g,
                                   (__attribute__((address_space(3))) void*)l, 16, 0, 0);
}

// ---------------- 128x128 GEMM with T2 swizzle (out-projection) ----------------
template <int MODE>
__global__ void k_gemm(const u16* __restrict__ A, const u16* __restrict__ Bw,
                       void* C0, void* C1, int Kd) {
  __shared__ u16 As[2][128 * 32];
  __shared__ u16 Bs[2][128 * 32];
  const int t = threadIdx.x;
  const int lane = t & 63, wv = t >> 6;
  const int wr = wv >> 1, wc = wv & 1;
  const int m0 = blockIdx.y * 128, n0 = blockIdx.x * 128;
  f32x4 acc[4][4] = {};
  const int NT = Kd / 32;

  auto stage = [&](int buf, int kt) {
    #pragma unroll
    for (int i = 0; i < 2; ++i) {
      int li = i * 256 + t;
      int row = li >> 2, kc = li & 3;
      int kcs = kc ^ ((row >> 1) & 3);
      const u16* ga = A + (size_t)(m0 + row) * Kd + kt * 32 + kcs * 8;
      gld_lds16(ga, &As[buf][(i * 256 + wv * 64) * 8]);
      const u16* gb = Bw + (size_t)(n0 + row) * Kd + kt * 32 + kcs * 8;
      gld_lds16(gb, &Bs[buf][(i * 256 + wv * 64) * 8]);
    }
  };

  stage(0, 0);
  __syncthreads();
  int buf = 0;
  const int l15 = lane & 15, l4 = lane >> 4;
  for (int kt = 0; kt < NT; ++kt) {
    if (kt + 1 < NT) stage(buf ^ 1, kt + 1);
    short8 af[4], bfr[4];
    #pragma unroll
    for (int m = 0; m < 4; ++m) {
      int row = wr * 64 + m * 16 + l15;
      int g = l4 ^ ((row >> 1) & 3);
      af[m] = *(const short8*)&As[buf][row * 32 + g * 8];
    }
    #pragma unroll
    for (int n = 0; n < 4; ++n) {
      int row = wc * 64 + n * 16 + l15;
      int g = l4 ^ ((row >> 1) & 3);
      bfr[n] = *(const short8*)&Bs[buf][row * 32 + g * 8];
    }
    #pragma unroll
    for (int m = 0; m < 4; ++m)
      #pragma unroll
      for (int n = 0; n < 4; ++n)
        acc[m][n] = MFMA16(af[m], bfr[n], acc[m][n]);
    __syncthreads();
    buf ^= 1;
  }
  #pragma unroll
  for (int m = 0; m < 4; ++m)
    #pragma unroll
    for (int n = 0; n < 4; ++n)
      #pragma unroll
      for (int e = 0; e < 4; ++e) {
        int row = m0 + wr * 64 + m * 16 + l4 * 4 + e;
        int col = n0 + wc * 64 + n * 16 + l15;
        if (MODE == 0) {
          ((float*)C0)[(size_t)row * 2048 + col] = acc[m][n][e];
        } else {
          u16 vb = f2bf(acc[m][n][e]);
          if (n0 < 6144) ((u16*)C0)[(size_t)row * 6144 + col] = vb;
          else           ((u16*)C1)[(size_t)row * 2048 + (col - 6144)] = vb;
        }
      }
}

// ---------------- 256x256 GEMM, m201-style 8-phase / 2-K-tile schedule ----------------
// 8 phases/iter, 16 MFMA each (one quadrant x K=64). Stages (region restaged >=1
// post-MFMA barrier after last read): ph2:A0h0' ph3:B0h0' ph4:B0h1' ph5:A0h1'
// ph6:A1h0' ph7:B1h0' ph8:B1h1'+A1h1'. Waits: end-ph4 vmcnt(6), end-ph8 vmcnt(8).
#define SBAR __builtin_amdgcn_s_barrier()
#define SCHB __builtin_amdgcn_sched_barrier(0)
#define LGKM0 asm volatile("s_waitcnt lgkmcnt(0)" ::: "memory")

template <int MODE>
__global__ __launch_bounds__(512)
void k_gemm8(const u16* __restrict__ A, const u16* __restrict__ Bw,
             void* C0, void* C1) {
  __shared__ u16 lds[65536];
  const int t = threadIdx.x;
  const int w = t >> 6, lane = t & 63;
  const int l15 = lane & 15, l4 = lane >> 4;
  const int wm = w >> 2, wn = w & 3;
  const int m0 = blockIdx.y * 256, n0 = blockIdx.x * 256;

  f32x4 acc[8][4] = {};
  short8 a[4][2], b[4][2];

  auto stageHalf = [&](int buf, int kt, int mat, int half) {
    const u16* src = mat ? Bw : A;
    const int row0 = (mat ? n0 : m0) + half * 128;
    u16* dst0 = &lds[mat * 32768 + (buf * 2 + half) * 8192 + w * 1024];
    #pragma unroll
    for (int i = 0; i < 2; ++i) {
      int f = w * 128 + i * 64 + lane;
      int rr = f >> 3, g = f & 7;
      const u16* ga = src + (size_t)(row0 + rr) * 2048 + kt * 64 + ((g ^ (rr & 7)) << 3);
      gld_lds16(ga, dst0 + i * 512);
    }
  };
  auto rdA = [&](int buf, int mq, int ks) {   // mq 0..7, half = mq>>2
    int row = wm * 64 + (mq & 3) * 16 + l15;
    int g = (l4 + ks * 4) ^ (row & 7);
    return *(const short8*)&lds[(buf * 2 + (mq >> 2)) * 8192 + row * 64 + g * 8];
  };
  auto rdB = [&](int buf, int n, int ks) {    // n 0..3, half = n>>1
    int row = wn * 32 + (n & 1) * 16 + l15;
    int g = (l4 + ks * 4) ^ (row & 7);
    return *(const short8*)&lds[32768 + (buf * 2 + (n >> 1)) * 8192 + row * 64 + g * 8];
  };
  auto quad = [&](int mB, int nB) {           // 16 MFMA: one C quadrant over K=64
    #pragma unroll
    for (int mq = 0; mq < 4; ++mq)
      #pragma unroll
      for (int nn = 0; nn < 2; ++nn) {
        acc[mB + mq][nB + nn] = MFMA16(a[mq][0], b[nB + nn][0], acc[mB + mq][nB + nn]);
        acc[mB + mq][nB + nn] = MFMA16(a[mq][1], b[nB + nn][1], acc[mB + mq][nB + nn]);
      }
  };

  // prologue: K-tiles 0 (buf0) and 1 (buf1), full drain
  stageHalf(0, 0, 0, 0); stageHalf(0, 0, 1, 0); stageHalf(0, 0, 1, 1); stageHalf(0, 0, 0, 1);
  stageHalf(1, 1, 0, 0); stageHalf(1, 1, 1, 0); stageHalf(1, 1, 1, 1); stageHalf(1, 1, 0, 1);
  asm volatile("s_waitcnt vmcnt(0)" ::: "memory");
  SBAR; SCHB;

  for (int it = 0; it < 16; ++it) {
    const int kt0 = 2 * it;
    const int st0 = (it < 15) ? kt0 + 2 : kt0;
    const int st1 = (it < 15) ? kt0 + 3 : kt0 + 1;

    // ---- ph1: reads a-lo(buf0), b01(buf0); MFMA (mlo,nlo)
    #pragma unroll
    for (int mq = 0; mq < 4; ++mq) { a[mq][0] = rdA(0, mq, 0); a[mq][1] = rdA(0, mq, 1); }
    #pragma unroll
    for (int n = 0; n < 2; ++n) { b[n][0] = rdB(0, n, 0); b[n][1] = rdB(0, n, 1); }
    SCHB; SBAR; LGKM0; SCHB;
    __builtin_amdgcn_s_setprio(1); quad(0, 0); __builtin_amdgcn_s_setprio(0);
    SBAR; SCHB;

    // ---- ph2: reads b23(buf0); stage A0h0'; MFMA (mlo,nhi)
    #pragma unroll
    for (int n = 2; n < 4; ++n) { b[n][0] = rdB(0, n, 0); b[n][1] = rdB(0, n, 1); }
    stageHalf(0, st0, 0, 0);
    SCHB; SBAR; LGKM0; SCHB;
    __builtin_amdgcn_s_setprio(1); quad(0, 2); __builtin_amdgcn_s_setprio(0);
    SBAR; SCHB;

    // ---- ph3: reads a-hi(buf0); stage B0h0'; MFMA (mhi,nhi)
    #pragma unroll
    for (int mq = 0; mq < 4; ++mq) { a[mq][0] = rdA(0, mq + 4, 0); a[mq][1] = rdA(0, mq + 4, 1); }
    stageHalf(0, st0, 1, 0);
    SCHB; SBAR; LGKM0; SCHB;
    __builtin_amdgcn_s_setprio(1); quad(4, 2); __builtin_amdgcn_s_setprio(0);
    SBAR; SCHB;

    // ---- ph4: no reads; stage B0h1'; MFMA (mhi,nlo); vmcnt(6)
    stageHalf(0, st0, 1, 1);
    SCHB; SBAR; LGKM0; SCHB;
    __builtin_amdgcn_s_setprio(1); quad(4, 0); __builtin_amdgcn_s_setprio(0);
    asm volatile("s_waitcnt vmcnt(6)" ::: "memory");
    SBAR; SCHB;

    // ---- ph5: reads a-lo(buf1), b01(buf1); stage A0h1'; MFMA (mlo,nlo)
    #pragma unroll
    for (int mq = 0; mq < 4; ++mq) { a[mq][0] = rdA(1, mq, 0); a[mq][1] = rdA(1, mq, 1); }
    #pragma unroll
    for (int n = 0; n < 2; ++n) { b[n][0] = rdB(1, n, 0); b[n][1] = rdB(1, n, 1); }
    stageHalf(0, st0, 0, 1);
    SCHB; SBAR; LGKM0; SCHB;
    __builtin_amdgcn_s_setprio(1); quad(0, 0); __builtin_amdgcn_s_setprio(0);
    SBAR; SCHB;

    // ---- ph6: reads b23(buf1); stage A1h0'; MFMA (mlo,nhi)
    #pragma unroll
    for (int n = 2; n < 4; ++n) { b[n][0] = rdB(1, n, 0); b[n][1] = rdB(1, n, 1); }
    stageHalf(1, st1, 0, 0);
    SCHB; SBAR; LGKM0; SCHB;
    __builtin_amdgcn_s_setprio(1); quad(0, 2); __builtin_amdgcn_s_setprio(0);
    SBAR; SCHB;

    // ---- ph7: reads a-hi(buf1); stage B1h0'; MFMA (mhi,nhi)
    #pragma unroll
    for (int mq = 0; mq < 4; ++mq) { a[mq][0] = rdA(1, mq + 4, 0); a[mq][1] = rdA(1, mq + 4, 1); }
    stageHalf(1, st1, 1, 0);
    SCHB; SBAR; LGKM0; SCHB;
    __builtin_amdgcn_s_setprio(1); quad(4, 2); __builtin_amdgcn_s_setprio(0);
    SBAR; SCHB;

    // ---- ph8: no reads; stage B1h1' + A1h1'; MFMA (mhi,nlo); vmcnt(8)
    stageHalf(1, st1, 1, 1);
    stageHalf(1, st1, 0, 1);
    SCHB; SBAR; LGKM0; SCHB;
    __builtin_amdgcn_s_setprio(1); quad(4, 0); __builtin_amdgcn_s_setprio(0);
    asm volatile("s_waitcnt vmcnt(8)" ::: "memory");
    SBAR; SCHB;
  }

  const bool toG = (MODE == 1) && (n0 >= 6144);
  #pragma unroll
  for (int mq = 0; mq < 8; ++mq) {
    int row = m0 + (mq >> 2) * 128 + wm * 64 + (mq & 3) * 16 + l4 * 4;
    #pragma unroll
    for (int n = 0; n < 4; ++n) {
      int col = n0 + (n >> 1) * 128 + wn * 32 + (n & 1) * 16 + l15;
      #pragma unroll
      for (int e = 0; e < 4; ++e) {
        if (MODE == 0) {
          ((float*)C0)[(size_t)(row + e) * 2048 + col] = acc[mq][n][e];
        } else {
          u16 vb = f2bf(acc[mq][n][e]);
          if (!toG) ((u16*)C0)[(size_t)(row + e) * 6144 + col] = vb;
          else      ((u16*)C1)[(size_t)(row + e) * 2048 + (col - 6144)] = vb;
        }
      }
    }
  }
}

// ---------------- causal depthwise conv (K=4) + SiLU ----------------
__global__ void k_conv(const u16* __restrict__ projQKV,
                       const float* __restrict__ qcw, const float* __restrict__ qcb,
                       const float* __restrict__ kcw, const float* __restrict__ kcb,
                       const float* __restrict__ vcw, const float* __restrict__ vcb,
                       u16* __restrict__ qkv2) {
  int idx = blockIdx.x * 256 + threadIdx.x;
  int cq = idx % 1536, rrow = idx / 1536;
  int c = cq * 4;
  int s = rrow & 2047, b = rrow >> 11;
  int type = c >> 11;             // 0=q,1=k,2=v
  int ch = c & 2047;
  int h = ch >> 7, d = ch & 127;
  const float* cw; const float* cb;
  if (type == 0)      { cw = qcw; cb = qcb; }
  else if (type == 1) { cw = kcw; cb = kcb; }
  else                { cw = vcw; cb = vcb; }
  float wch[4][4];
  #pragma unroll
  for (int u = 0; u < 4; ++u) {
    float4 wv = *(const float4*)(cw + (ch + u) * 4);
    wch[u][0] = wv.x; wch[u][1] = wv.y; wch[u][2] = wv.z; wch[u][3] = wv.w;
  }
  float4 bv = *(const float4*)(cb + ch);
  float accv[4] = {bv.x, bv.y, bv.z, bv.w};
  #pragma unroll
  for (int j = 0; j < 4; ++j) {
    int sj = s - 3 + j;
    if (sj < 0) continue;
    const u16* p = projQKV + (size_t)(rrow + j - 3) * 6144 + c;
    u32 pa = *(const u32*)p;
    u32 pb = *(const u32*)(p + 2);
    accv[0] += bflo(pa) * wch[0][j];
    accv[1] += bfhi(pa) * wch[1][j];
    accv[2] += bflo(pb) * wch[2][j];
    accv[3] += bfhi(pb) * wch[3][j];
  }
  u16 o4[4];
  #pragma unroll
  for (int u = 0; u < 4; ++u) {
    float y = accv[u];
    float sv = y * sigm(y);
    if (type == 1) sv *= 0.08838834764831845f;  // D^-0.5
    o4[u] = f2bf(sv);
  }
  int off = (type == 1 ? 0 : (type == 0 ? 128 : 256)) + d;
  u16* dst = qkv2 + ((size_t)(b * 16 + h) * 2048 + s) * 384 + off;
  *(u32*)dst       = (u32)o4[0] | ((u32)o4[1] << 16);
  *(u32*)(dst + 2) = (u32)o4[2] | ((u32)o4[3] << 16);
}

// ---------------- Phase A: per-(head,chunk) WY precompute ----------------
__global__ __launch_bounds__(256)
void k_chunkA(const u16* __restrict__ qkv2, const float* __restrict__ ab2,
              u16* __restrict__ Tbv, u16* __restrict__ nTbk,
              u16* __restrict__ Aq, float* __restrict__ vecs,
              u16* __restrict__ Kt) {
  __shared__ u16 Kl[64][136], Ql[64][136];
  __shared__ float Gk[4096], Gq[4096];
  __shared__ float clL[64], laL[64], bL[64], gpL[64];
  const int unit = blockIdx.x;
  const int bh = unit >> 5, c = unit & 31;
  const int t = threadIdx.x;
  const int wv = t >> 6, lane = t & 63;
  const int l15 = lane & 15, l4 = lane >> 4;
  const u16* qb = qkv2 + ((size_t)bh * 2048 + c * 64) * 384;

  #pragma unroll
  for (int p = 0; p < 4; ++p) {
    int ld = p * 256 + t;
    int row = ld >> 4, c8 = (ld & 15) * 8;
    *(uint4*)&Kl[row][c8] = *(const uint4*)(qb + (size_t)row * 384 + c8);
    *(uint4*)&Ql[row][c8] = *(const uint4*)(qb + (size_t)row * 384 + 128 + c8);
  }
  if (wv == 0) {
    float2 abv = *(const float2*)(ab2 + ((size_t)bh * 2048 + c * 64 + lane) * 2);
    float la = log2f(abv.x);
    float cl = la;
    #pragma unroll
    for (int o = 1; o < 64; o <<= 1) {
      float nv = __shfl_up(cl, o, 64);
      if (lane >= o) cl += nv;
    }
    clL[lane] = cl; laL[lane] = la; bL[lane] = abv.y;
    gpL[lane] = exp2f(cl - la);
  }
  __syncthreads();

  {
    const int t0 = (wv >> 1) * 32, i0 = (wv & 1) * 32;
    f32x4 ak[2][2] = {}, aq[2][2] = {};
    #pragma unroll
    for (int ks = 0; ks < 4; ++ks) {
      short8 bk[2], Ka[2], Qa[2];
      #pragma unroll
      for (int n = 0; n < 2; ++n)
        bk[n] = *(const short8*)&Kl[i0 + n * 16 + l15][ks * 32 + l4 * 8];
      #pragma unroll
      for (int m = 0; m < 2; ++m) {
        Ka[m] = *(const short8*)&Kl[t0 + m * 16 + l15][ks * 32 + l4 * 8];
        Qa[m] = *(const short8*)&Ql[t0 + m * 16 + l15][ks * 32 + l4 * 8];
      }
      #pragma unroll
      for (int m = 0; m < 2; ++m)
        #pragma unroll
        for (int n = 0; n < 2; ++n) {
          ak[m][n] = MFMA16(Ka[m], bk[n], ak[m][n]);
          aq[m][n] = MFMA16(Qa[m], bk[n], aq[m][n]);
        }
    }
    #pragma unroll
    for (int m = 0; m < 2; ++m)
      #pragma unroll
      for (int n = 0; n < 2; ++n)
        #pragma unroll
        for (int e = 0; e < 4; ++e) {
          int row = t0 + m * 16 + l4 * 4 + e;
          int col = i0 + n * 16 + l15;
          Gk[row * 64 + col] = ak[m][n][e];
          Gq[row * 64 + col] = aq[m][n][e];
        }
  }
  __syncthreads();

  #pragma unroll
  for (int p = 0; p < 16; ++p) {
    int e = p * 256 + t; int tt = e >> 6, ii = e & 63;
    float lv = 0.f;
    if (ii < tt) lv = bL[tt] * Gk[e] * exp2f(clL[tt] - laL[tt] - clL[ii]);
    float av = (ii <= tt) ? Gq[e] * exp2f(clL[tt] - clL[ii]) : 0.f;
    Gk[e] = lv;
    Aq[(size_t)unit * 4096 + e] = f2bf(av);
  }
  __syncthreads();

  float X[64];
  if (t < 128) {
    #pragma unroll
    for (int r = 0; r < 64; ++r)
      X[r] = bL[r] * bf2f(qb[(size_t)r * 384 + 256 + t]);
  } else {
    int ck = t - 128;
    #pragma unroll
    for (int r = 0; r < 64; ++r)
      X[r] = -bL[r] * gpL[r] * bf2f(Kl[r][ck]);
  }
  #pragma unroll
  for (int i = 0; i < 63; ++i) {
    float xi = X[i];
    #pragma unroll
    for (int r = i + 1; r < 64; ++r)
      X[r] = fmaf(-Gk[r * 64 + i], xi, X[r]);
  }
  if (t < 128) {
    #pragma unroll
    for (int r = 0; r < 64; ++r)
      Tbv[(size_t)unit * 8192 + r * 128 + t] = f2bf(X[r]);
  } else {
    #pragma unroll
    for (int r = 0; r < 64; ++r)
      nTbk[(size_t)unit * 8192 + r * 128 + (t - 128)] = f2bf(X[r]);
  }
  if (t < 64) {
    vecs[(size_t)unit * 128 + t] = exp2f(clL[t]);
    vecs[(size_t)unit * 128 + 64 + t] = exp2f(clL[63] - clL[t]);
  }
  {
    int dk = t >> 1, tt0 = (t & 1) * 32;
    uint4 w[4];
    u16* wp = (u16*)w;
    #pragma unroll
    for (int j = 0; j < 32; ++j) wp[j] = Kl[tt0 + j][dk];
    uint4* dst = (uint4*)(Kt + (size_t)unit * 8192 + dk * 64 + tt0);
    dst[0] = w[0]; dst[1] = w[1]; dst[2] = w[2]; dst[3] = w[3];
  }
}

// ---------------- Phase B v2: 256 blocks (32 heads x 8 dv-slices of 16) ----------------
#define OFF_NT  0
#define OFF_AQ  8192
#define OFF_Q   12288
#define OFF_KT  20480
#define OFF_TBV 28672
#define STG_U16 29696

__global__ __launch_bounds__(256)
void k_chunkB(const u16* __restrict__ qkv2, const u16* __restrict__ Tbv,
              const u16* __restrict__ nTbk, const u16* __restrict__ Aq,
              const u16* __restrict__ Kt, const float* __restrict__ vecs,
              float* __restrict__ o) {
  __shared__ u16 stg[2][STG_U16];
  __shared__ float S[16 * 132];
  __shared__ u16 Ut[16 * 72], Utd[16 * 72];
  __shared__ float gdl[2][128];
  const int bid = blockIdx.x;
  const int xcd = bid & 7, within = bid >> 3;
  const int sl = within & 7, hgrp = within >> 3;
  const int bh = hgrp * 8 + xcd;
  const int dv0 = sl * 16;
  const int b = bh >> 4, h = bh & 15;
  const int t = threadIdx.x;
  const int wv = t >> 6, lane = t & 63;
  const int l15 = lane & 15, l4 = lane >> 4;
  const int t0 = wv * 16;
  const int dk0 = wv * 32;
  const u16* qbase = qkv2 + (size_t)bh * 2048 * 384;
  float* obase = o + (size_t)b * 2048 * 2048 + h * 128 + dv0;

  for (int p = t; p < 16 * 132; p += 256) S[p] = 0.f;

  auto stage = [&](int buf, int c) {
    u16* sb = &stg[buf][0];
    const size_t unit = (size_t)bh * 32 + c;
    const u16* tbk = nTbk + unit * 8192;
    const u16* aqp = Aq + unit * 4096;
    const u16* ktp = Kt + unit * 8192;
    const u16* tbv = Tbv + unit * 8192;
    const u16* qp  = qbase + (size_t)c * 64 * 384 + 128;
    #pragma unroll
    for (int r = 0; r < 4; ++r) {
      int f = r * 256 + t; int rr = f >> 4, c16 = f & 15;
      gld_lds16(tbk + rr * 128 + (c16 ^ (rr & 7)) * 8, sb + OFF_NT + (r * 256 + wv * 64) * 8);
    }
    #pragma unroll
    for (int r = 0; r < 2; ++r) {
      int f = r * 256 + t; int rr = f >> 3, c8 = f & 7;
      gld_lds16(aqp + rr * 64 + (c8 ^ (rr & 7)) * 8, sb + OFF_AQ + (r * 256 + wv * 64) * 8);
    }
    #pragma unroll
    for (int r = 0; r < 4; ++r) {
      int f = r * 256 + t; int rr = f >> 4, c16 = f & 15;
      gld_lds16(qp + rr * 384 + (c16 ^ (rr & 7)) * 8, sb + OFF_Q + (r * 256 + wv * 64) * 8);
    }
    #pragma unroll
    for (int r = 0; r < 4; ++r) {
      int f = r * 256 + t; int rr = f >> 3, c8 = f & 7;
      gld_lds16(ktp + rr * 64 + (c8 ^ (rr & 7)) * 8, sb + OFF_KT + (r * 256 + wv * 64) * 8);
    }
    if (t < 128)
      gld_lds16(tbv + (t >> 1) * 128 + dv0 + (t & 1) * 8, sb + OFF_TBV + wv * 64 * 8);
  };

  stage(0, 0);
  if (t < 128) gdl[0][t] = vecs[(size_t)bh * 32 * 128 + t];
  __syncthreads();

  for (int c = 0; c < 32; ++c) {
    const int buf = c & 1;
    const u16* sb = &stg[buf][0];
    float vnext = 0.f;
    if (c + 1 < 32) {
      stage(buf ^ 1, c + 1);
      if (t < 128) vnext = vecs[((size_t)bh * 32 + c + 1) * 128 + t];
    }

    f32x4 acc1 = {}, acc2 = {};
    #pragma unroll
    for (int e = 0; e < 4; ++e)
      acc1[e] = bf2f(sb[OFF_TBV + (t0 + l4 * 4 + e) * 16 + l15]);
    #pragma unroll
    for (int ks = 0; ks < 4; ++ks) {
      short8 bhi, blo;
      {
        const float* srow = &S[l15 * 132 + ks * 32 + l4 * 8];
        float4 s0 = *(const float4*)srow, s1 = *(const float4*)(srow + 4);
        float sv[8] = {s0.x, s0.y, s0.z, s0.w, s1.x, s1.y, s1.z, s1.w};
        #pragma unroll
        for (int j = 0; j < 8; ++j) {
          u16 hv = f2bf(sv[j]);
          bhi[j] = (short)hv;
          blo[j] = (short)f2bf(sv[j] - bf2f(hv));
        }
      }
      const int cx = ((ks * 4 + l4) ^ (l15 & 7)) * 8;
      short8 a1 = *(const short8*)&sb[OFF_NT + (t0 + l15) * 128 + cx];
      short8 a2 = *(const short8*)&sb[OFF_Q + (t0 + l15) * 128 + cx];
      acc1 = MFMA16(a1, bhi, acc1);
      acc1 = MFMA16(a1, blo, acc1);
      acc2 = MFMA16(a2, bhi, acc2);
      acc2 = MFMA16(a2, blo, acc2);
    }
    {
      u16 up[4], ud[4];
      #pragma unroll
      for (int e = 0; e < 4; ++e) {
        float uv = acc1[e];
        up[e] = f2bf(uv);
        ud[e] = f2bf(uv * gdl[buf][64 + t0 + l4 * 4 + e]);
      }
      int ux = l15 * 72 + t0 + l4 * 4;
      *(u32*)&Ut[ux]      = (u32)up[0] | ((u32)up[1] << 16);
      *(u32*)&Ut[ux + 2]  = (u32)up[2] | ((u32)up[3] << 16);
      *(u32*)&Utd[ux]     = (u32)ud[0] | ((u32)ud[1] << 16);
      *(u32*)&Utd[ux + 2] = (u32)ud[2] | ((u32)ud[3] << 16);
    }
    asm volatile("s_waitcnt lgkmcnt(0)" ::: "memory");
    __builtin_amdgcn_s_barrier();
    __builtin_amdgcn_sched_barrier(0);

    #pragma unroll
    for (int e = 0; e < 4; ++e) acc2[e] *= gdl[buf][t0 + l4 * 4 + e];
    #pragma unroll
    for (int ks = 0; ks < 2; ++ks) {
      const int cx = ((ks * 4 + l4) ^ (l15 & 7)) * 8;
      short8 af = *(const short8*)&sb[OFF_AQ + (t0 + l15) * 64 + cx];
      short8 bf_ = *(const short8*)&Ut[l15 * 72 + ks * 32 + l4 * 8];
      acc2 = MFMA16(af, bf_, acc2);
    }
    #pragma unroll
    for (int e = 0; e < 4; ++e)
      obase[(size_t)(c * 64 + t0 + l4 * 4 + e) * 2048 + l15] = acc2[e];

    f32x4 acc3[2] = {};
    #pragma unroll
    for (int ks = 0; ks < 2; ++ks) {
      short8 a3 = *(const short8*)&Utd[l15 * 72 + ks * 32 + l4 * 8];
      #pragma unroll
      for (int n = 0; n < 2; ++n) {
        const int kr = dk0 + n * 16 + l15;
        const int cx = ((ks * 4 + l4) ^ (l15 & 7)) * 8;
        short8 b3 = *(const short8*)&sb[OFF_KT + kr * 64 + cx];
        acc3[n] = MFMA16(a3, b3, acc3[n]);
      }
    }
    float gtot = gdl[buf][63];
    #pragma unroll
    for (int n = 0; n < 2; ++n)
      #pragma unroll
      for (int e = 0; e < 4; ++e) {
        float* sp = &S[(l4 * 4 + e) * 132 + dk0 + n * 16 + l15];
        *sp = gtot * *sp + acc3[n][e];
      }
    if (c + 1 < 32 && t < 128) gdl[buf ^ 1][t] = vnext;
    __syncthreads();
  }
}

// ---------------- LayerNorm(D) + sigmoid-gate, write bf16 ----------------
__global__ void k_lng(const float* __restrict__ o, const u16* __restrict__ projG,
                      const float* __restrict__ ln_w, const float* __restrict__ ln_b,
                      u16* __restrict__ og) {
  int gidx = blockIdx.x * 4 + (threadIdx.x >> 6);
  int lane = threadIdx.x & 63;
  int rrow = gidx >> 4, h = gidx & 15;
  const float* op = o + (size_t)rrow * 2048 + h * 128;
  float2 x2 = *(const float2*)(op + lane * 2);
  float sum = x2.x + x2.y, sq = x2.x * x2.x + x2.y * x2.y;
  #pragma unroll
  for (int m = 1; m < 64; m <<= 1) {
    sum += __shfl_xor(sum, m, 64);
    sq  += __shfl_xor(sq, m, 64);
  }
  float mu = sum * (1.f / 128.f);
  float var = sq * (1.f / 128.f) - mu * mu;
  float rs = 1.0f / sqrtf(var + 1e-5f);
  u32 gu = *(const u32*)(projG + (size_t)rrow * 2048 + h * 128 + lane * 2);
  float g0 = sigm(bflo(gu)), g1 = sigm(bfhi(gu));
  int d0 = lane * 2;
  float y0 = ((x2.x - mu) * rs * ln_w[d0] + ln_b[d0]) * g0;
  float y1 = ((x2.y - mu) * rs * ln_w[d0 + 1] + ln_b[d0 + 1]) * g1;
  *(u32*)(og + (size_t)rrow * 2048 + h * 128 + d0) = (u32)f2bf(y0) | ((u32)f2bf(y1) << 16);
}

extern "C" void kernel_launch(void* const* d_in, const int* in_sizes, int n_in,
                              void* d_out, int out_size, void* d_ws, size_t ws_size,
                              hipStream_t stream) {
  const float* x   = (const float*)d_in[0];
  const float* Wq  = (const float*)d_in[1];
  const float* Wk  = (const float*)d_in[2];
  const float* Wv  = (const float*)d_in[3];
  const float* Wa  = (const float*)d_in[4];
  const float* ba  = (const float*)d_in[5];
  const float* Wb  = (const float*)d_in[6];
  const float* bb  = (const float*)d_in[7];
  const float* Wg  = (const float*)d_in[8];
  const float* Wo  = (const float*)d_in[9];
  const float* qcw = (const float*)d_in[10];
  const float* qcb = (const float*)d_in[11];
  const float* kcw = (const float*)d_in[12];
  const float* kcb = (const float*)d_in[13];
  const float* vcw = (const float*)d_in[14];
  const float* vcb = (const float*)d_in[15];
  const float* lnw = (const float*)d_in[16];
  const float* lnb = (const float*)d_in[17];
  float* out = (float*)d_out;

  if (ws_size < 168820736ull) return;  // canary
  char* ws = (char*)d_ws;
  u16*   xb   = (u16*)(ws);
  u16*   Kt   = (u16*)(ws);
  u16*   og   = (u16*)(ws);
  u16*   Wt   = (u16*)(ws + 16777216);
  u16*   Wot  = (u16*)(ws + 16777216);
  u16*   Tbv  = (u16*)(ws + 25165824);
  u16*   Aq   = (u16*)(ws + 41943040);
  u16*   pQKV = (u16*)(ws + 50331648);
  float* oB   = (float*)(ws + 50331648);
  u16*   nTbk = (u16*)(ws + 83886080);
  u16*   pG   = (u16*)(ws + 100663296);
  u16*   qkv2 = (u16*)(ws + 117440512);
  float* ab2  = (float*)(ws + 167772160);
  float* vecs = (float*)(ws + 168296448);

  k_cvt_x<<<4096, 256, 0, stream>>>(x, xb);
  k_tconv4<<<dim3(64, 64, 4), 256, 0, stream>>>(Wq, Wk, Wv, Wg, Wt);
  k_ab<<<512, 256, 0, stream>>>(x, Wa, ba, Wb, bb, ab2);

  // fused QKVG projection: [4096 x 2048] @ [2048 x 8192] -> bf16 split (8-phase)
  k_gemm8<1><<<dim3(32, 16), 512, 0, stream>>>(xb, Wt, pQKV, pG);
  k_tconv<<<dim3(64, 64), 256, 0, stream>>>(Wo, Wot);
  k_conv<<<24576, 256, 0, stream>>>(pQKV, qcw, qcb, kcw, kcb, vcw, vcb, qkv2);
  k_chunkA<<<1024, 256, 0, stream>>>(qkv2, ab2, Tbv, nTbk, Aq, vecs, Kt);
  k_chunkB<<<256, 256, 0, stream>>>(qkv2, Tbv, nTbk, Aq, Kt, vecs, oB);
  k_lng<<<16384, 256, 0, stream>>>(oB, pG, lnw, lnb, og);
  k_gemm<0><<<dim3(16, 32), 256, 0, stream>>>(og, Wot, out, nullptr, 2048);
}

// Round 11
// 470.914 us; speedup vs baseline: 1.0017x; 1.0017x over previous
//
#include <hip/hip_runtime.h>
#include <math.h>
#include <stdint.h>

typedef unsigned short u16;
typedef unsigned int u32;
typedef __attribute__((ext_vector_type(8))) short short8;
typedef __attribute__((ext_vector_type(4))) float f32x4;

#define MFMA16(a, b, c) __builtin_amdgcn_mfma_f32_16x16x32_bf16(a, b, c, 0, 0, 0)

__device__ __forceinline__ u16 f2bf(float f) {
  union { float f; u32 u; } v; v.f = f;
  return (u16)((v.u + 0x7FFFu + ((v.u >> 16) & 1u)) >> 16);
}
__device__ __forceinline__ float bf2f(u16 h) {
  union { u32 u; float f; } v; v.u = ((u32)h) << 16; return v.f;
}
__device__ __forceinline__ float bflo(u32 p) {
  union { u32 u; float f; } v; v.u = p << 16; return v.f;
}
__device__ __forceinline__ float bfhi(u32 p) {
  union { u32 u; float f; } v; v.u = p & 0xffff0000u; return v.f;
}
__device__ __forceinline__ float sigm(float x) { return 1.f / (1.f + expf(-x)); }

// ---------------- x -> bf16 ----------------
__global__ void k_cvt_x(const float* __restrict__ x, u16* __restrict__ xb) {
  int i = (blockIdx.x * 256 + threadIdx.x) * 8;
  float4 a = *(const float4*)(x + i);
  float4 b = *(const float4*)(x + i + 4);
  uint4 p;
  p.x = (u32)f2bf(a.x) | ((u32)f2bf(a.y) << 16);
  p.y = (u32)f2bf(a.z) | ((u32)f2bf(a.w) << 16);
  p.z = (u32)f2bf(b.x) | ((u32)f2bf(b.y) << 16);
  p.w = (u32)f2bf(b.z) | ((u32)f2bf(b.w) << 16);
  *(uint4*)(xb + i) = p;
}

// ---------------- 4x W transpose: [K][N] f32 -> [N][K] bf16 ----------------
__global__ void k_tconv4(const float* __restrict__ W0, const float* __restrict__ W1,
                         const float* __restrict__ W2, const float* __restrict__ W3,
                         u16* __restrict__ Wt) {
  __shared__ float tile[32][33];
  int z = blockIdx.z;
  const float* W = (z == 0) ? W0 : (z == 1) ? W1 : (z == 2) ? W2 : W3;
  u16* dst = Wt + (size_t)z * 2048 * 2048;
  int n0 = blockIdx.x * 32, k0 = blockIdx.y * 32;
  int tc = threadIdx.x & 31, tr = threadIdx.x >> 5;
  #pragma unroll
  for (int p = 0; p < 4; ++p) {
    int k = k0 + p * 8 + tr;
    tile[p * 8 + tr][tc] = W[(size_t)k * 2048 + n0 + tc];
  }
  __syncthreads();
  #pragma unroll
  for (int p = 0; p < 4; ++p) {
    int n = n0 + p * 8 + tr;
    dst[(size_t)n * 2048 + k0 + tc] = f2bf(tile[tc][p * 8 + tr]);
  }
}

__global__ void k_tconv(const float* __restrict__ W, u16* __restrict__ Wt) {
  __shared__ float tile[32][33];
  int n0 = blockIdx.x * 32, k0 = blockIdx.y * 32;
  int tc = threadIdx.x & 31, tr = threadIdx.x >> 5;
  #pragma unroll
  for (int p = 0; p < 4; ++p) {
    int k = k0 + p * 8 + tr;
    tile[p * 8 + tr][tc] = W[(size_t)k * 2048 + n0 + tc];
  }
  __syncthreads();
  #pragma unroll
  for (int p = 0; p < 4; ++p) {
    int n = n0 + p * 8 + tr;
    Wt[(size_t)n * 2048 + k0 + tc] = f2bf(tile[tc][p * 8 + tr]);
  }
}

// ---------------- alpha/beta GEMV, LDS-tiled f32 ----------------
__global__ __launch_bounds__(256)
void k_ab(const float* __restrict__ x, const float* __restrict__ Wa,
          const float* __restrict__ ba, const float* __restrict__ Wb,
          const float* __restrict__ bb, float* __restrict__ ab2) {
  __shared__ float Wl[128 * 32];
  __shared__ float xl[8][128];
  const int t = threadIdx.x;
  const int lr = t >> 5, c = t & 31;
  const int r0 = blockIdx.x * 8;
  const int ch = c & 15;
  float acc = 0.f;
  for (int kt = 0; kt < 16; ++kt) {
    #pragma unroll
    for (int i = 0; i < 16; ++i) {
      int idx = i * 256 + t;
      int kk = idx >> 5, cc = idx & 31;
      const float* Ws = (cc < 16) ? Wa : Wb;
      Wl[kk * 32 + cc] = Ws[(kt * 128 + kk) * 16 + (cc & 15)];
    }
    #pragma unroll
    for (int i = 0; i < 4; ++i) {
      int idx = i * 256 + t;
      int rr = idx >> 7, kk = idx & 127;
      xl[rr][kk] = x[(size_t)(r0 + rr) * 2048 + kt * 128 + kk];
    }
    __syncthreads();
    #pragma unroll
    for (int kk = 0; kk < 128; kk += 4) {
      float2 x01 = *(const float2*)&xl[lr][kk];
      float2 x23 = *(const float2*)&xl[lr][kk + 2];
      acc += x01.x * Wl[(kk + 0) * 32 + c] + x01.y * Wl[(kk + 1) * 32 + c]
           + x23.x * Wl[(kk + 2) * 32 + c] + x23.y * Wl[(kk + 3) * 32 + c];
    }
    __syncthreads();
  }
  acc += (c < 16) ? ba[ch] : bb[ch];
  float sg = sigm(acc);
  int rowi = r0 + lr;
  int b = rowi >> 11, s = rowi & 2047;
  size_t base = ((size_t)(b * 16 + ch) * 2048 + s) * 2;
  if (c < 16) ab2[base + 0] = sg;
  else        ab2[base + 1] = sg;
}

__device__ __forceinline__ void gld_lds16(const u16* g, u16* l) {
  __builtin_amdgcn_global_load_lds((const __attribute__((address_space(1))) void*)g,
                                   (__attribute__((address_space(3))) void*)l, 16, 0, 0);
}

// ---------------- 128x128 GEMM with T2 swizzle (out-projection) ----------------
template <int MODE>
__global__ void k_gemm(const u16* __restrict__ A, const u16* __restrict__ Bw,
                       void* C0, void* C1, int Kd) {
  __shared__ u16 As[2][128 * 32];
  __shared__ u16 Bs[2][128 * 32];
  const int t = threadIdx.x;
  const int lane = t & 63, wv = t >> 6;
  const int wr = wv >> 1, wc = wv & 1;
  const int m0 = blockIdx.y * 128, n0 = blockIdx.x * 128;
  f32x4 acc[4][4] = {};
  const int NT = Kd / 32;

  auto stage = [&](int buf, int kt) {
    #pragma unroll
    for (int i = 0; i < 2; ++i) {
      int li = i * 256 + t;
      int row = li >> 2, kc = li & 3;
      int kcs = kc ^ ((row >> 1) & 3);
      const u16* ga = A + (size_t)(m0 + row) * Kd + kt * 32 + kcs * 8;
      gld_lds16(ga, &As[buf][(i * 256 + wv * 64) * 8]);
      const u16* gb = Bw + (size_t)(n0 + row) * Kd + kt * 32 + kcs * 8;
      gld_lds16(gb, &Bs[buf][(i * 256 + wv * 64) * 8]);
    }
  };

  stage(0, 0);
  __syncthreads();
  int buf = 0;
  const int l15 = lane & 15, l4 = lane >> 4;
  for (int kt = 0; kt < NT; ++kt) {
    if (kt + 1 < NT) stage(buf ^ 1, kt + 1);
    short8 af[4], bfr[4];
    #pragma unroll
    for (int m = 0; m < 4; ++m) {
      int row = wr * 64 + m * 16 + l15;
      int g = l4 ^ ((row >> 1) & 3);
      af[m] = *(const short8*)&As[buf][row * 32 + g * 8];
    }
    #pragma unroll
    for (int n = 0; n < 4; ++n) {
      int row = wc * 64 + n * 16 + l15;
      int g = l4 ^ ((row >> 1) & 3);
      bfr[n] = *(const short8*)&Bs[buf][row * 32 + g * 8];
    }
    #pragma unroll
    for (int m = 0; m < 4; ++m)
      #pragma unroll
      for (int n = 0; n < 4; ++n)
        acc[m][n] = MFMA16(af[m], bfr[n], acc[m][n]);
    __syncthreads();
    buf ^= 1;
  }
  #pragma unroll
  for (int m = 0; m < 4; ++m)
    #pragma unroll
    for (int n = 0; n < 4; ++n)
      #pragma unroll
      for (int e = 0; e < 4; ++e) {
        int row = m0 + wr * 64 + m * 16 + l4 * 4 + e;
        int col = n0 + wc * 64 + n * 16 + l15;
        if (MODE == 0) {
          ((float*)C0)[(size_t)row * 2048 + col] = acc[m][n][e];
        } else {
          u16 vb = f2bf(acc[m][n][e]);
          if (n0 < 6144) ((u16*)C0)[(size_t)row * 6144 + col] = vb;
          else           ((u16*)C1)[(size_t)row * 2048 + (col - 6144)] = vb;
        }
      }
}

// ---------------- 256x256 GEMM, BK=32, 64KB LDS -> 2 blocks/CU (QKVG) ----------------
// m97-style: stage(kt+1) -> 12 frag reads -> 32 MFMA -> __syncthreads.
// Occupancy experiment: co-resident block hides barrier drain (m114 mechanism).
template <int MODE>
__global__ __launch_bounds__(512)
void k_gemm8(const u16* __restrict__ A, const u16* __restrict__ Bw,
             void* C0, void* C1) {
  __shared__ u16 lds[32768];   // A: [2][256][32] @0 ; B: same @16384 (64KB total)
  const int t = threadIdx.x;
  const int w = t >> 6, lane = t & 63;
  const int l15 = lane & 15, l4 = lane >> 4;
  const int wm = w >> 2, wn = w & 3;
  const int m0 = blockIdx.y * 256, n0 = blockIdx.x * 256;

  f32x4 acc[8][4] = {};

  auto stage = [&](int buf, int kt) {
    #pragma unroll
    for (int i = 0; i < 2; ++i) {
      int f = w * 128 + i * 64 + lane;          // [0,1024): rr=f>>2, g=f&3
      int rr = f >> 2, g = f & 3;
      int gs = g ^ ((rr >> 1) & 3);             // pre-swizzled source granule
      const u16* ga = A + (size_t)(m0 + rr) * 2048 + kt * 32 + gs * 8;
      gld_lds16(ga, &lds[buf * 8192 + f * 8]);
      const u16* gb = Bw + (size_t)(n0 + rr) * 2048 + kt * 32 + gs * 8;
      gld_lds16(gb, &lds[16384 + buf * 8192 + f * 8]);
    }
  };
  auto rdA = [&](int buf, int mq) {            // mq 0..7 (half = mq>>2)
    int row = (mq >> 2) * 128 + wm * 64 + (mq & 3) * 16 + l15;
    int g = l4 ^ ((row >> 1) & 3);
    return *(const short8*)&lds[buf * 8192 + row * 32 + g * 8];
  };
  auto rdB = [&](int buf, int n) {             // n 0..3 (half = n>>1)
    int row = (n >> 1) * 128 + wn * 32 + (n & 1) * 16 + l15;
    int g = l4 ^ ((row >> 1) & 3);
    return *(const short8*)&lds[16384 + buf * 8192 + row * 32 + g * 8];
  };

  stage(0, 0);
  __syncthreads();

  for (int kt = 0; kt < 64; ++kt) {
    const int buf = kt & 1;
    if (kt + 1 < 64) stage(buf ^ 1, kt + 1);
    short8 a[8], b[4];
    #pragma unroll
    for (int mq = 0; mq < 8; ++mq) a[mq] = rdA(buf, mq);
    #pragma unroll
    for (int n = 0; n < 4; ++n) b[n] = rdB(buf, n);
    #pragma unroll
    for (int mq = 0; mq < 8; ++mq)
      #pragma unroll
      for (int n = 0; n < 4; ++n)
        acc[mq][n] = MFMA16(a[mq], b[n], acc[mq][n]);
    __syncthreads();
  }

  const bool toG = (MODE == 1) && (n0 >= 6144);
  #pragma unroll
  for (int mq = 0; mq < 8; ++mq) {
    int row = m0 + (mq >> 2) * 128 + wm * 64 + (mq & 3) * 16 + l4 * 4;
    #pragma unroll
    for (int n = 0; n < 4; ++n) {
      int col = n0 + (n >> 1) * 128 + wn * 32 + (n & 1) * 16 + l15;
      #pragma unroll
      for (int e = 0; e < 4; ++e) {
        if (MODE == 0) {
          ((float*)C0)[(size_t)(row + e) * 2048 + col] = acc[mq][n][e];
        } else {
          u16 vb = f2bf(acc[mq][n][e]);
          if (!toG) ((u16*)C0)[(size_t)(row + e) * 6144 + col] = vb;
          else      ((u16*)C1)[(size_t)(row + e) * 2048 + (col - 6144)] = vb;
        }
      }
    }
  }
}

// ---------------- causal depthwise conv (K=4) + SiLU ----------------
__global__ void k_conv(const u16* __restrict__ projQKV,
                       const float* __restrict__ qcw, const float* __restrict__ qcb,
                       const float* __restrict__ kcw, const float* __restrict__ kcb,
                       const float* __restrict__ vcw, const float* __restrict__ vcb,
                       u16* __restrict__ qkv2) {
  int idx = blockIdx.x * 256 + threadIdx.x;
  int cq = idx % 1536, rrow = idx / 1536;
  int c = cq * 4;
  int s = rrow & 2047, b = rrow >> 11;
  int type = c >> 11;             // 0=q,1=k,2=v
  int ch = c & 2047;
  int h = ch >> 7, d = ch & 127;
  const float* cw; const float* cb;
  if (type == 0)      { cw = qcw; cb = qcb; }
  else if (type == 1) { cw = kcw; cb = kcb; }
  else                { cw = vcw; cb = vcb; }
  float wch[4][4];
  #pragma unroll
  for (int u = 0; u < 4; ++u) {
    float4 wv = *(const float4*)(cw + (ch + u) * 4);
    wch[u][0] = wv.x; wch[u][1] = wv.y; wch[u][2] = wv.z; wch[u][3] = wv.w;
  }
  float4 bv = *(const float4*)(cb + ch);
  float accv[4] = {bv.x, bv.y, bv.z, bv.w};
  #pragma unroll
  for (int j = 0; j < 4; ++j) {
    int sj = s - 3 + j;
    if (sj < 0) continue;
    const u16* p = projQKV + (size_t)(rrow + j - 3) * 6144 + c;
    u32 pa = *(const u32*)p;
    u32 pb = *(const u32*)(p + 2);
    accv[0] += bflo(pa) * wch[0][j];
    accv[1] += bfhi(pa) * wch[1][j];
    accv[2] += bflo(pb) * wch[2][j];
    accv[3] += bfhi(pb) * wch[3][j];
  }
  u16 o4[4];
  #pragma unroll
  for (int u = 0; u < 4; ++u) {
    float y = accv[u];
    float sv = y * sigm(y);
    if (type == 1) sv *= 0.08838834764831845f;  // D^-0.5
    o4[u] = f2bf(sv);
  }
  int off = (type == 1 ? 0 : (type == 0 ? 128 : 256)) + d;
  u16* dst = qkv2 + ((size_t)(b * 16 + h) * 2048 + s) * 384 + off;
  *(u32*)dst       = (u32)o4[0] | ((u32)o4[1] << 16);
  *(u32*)(dst + 2) = (u32)o4[2] | ((u32)o4[3] << 16);
}

// ---------------- Phase A: per-(head,chunk) WY precompute ----------------
__global__ __launch_bounds__(256)
void k_chunkA(const u16* __restrict__ qkv2, const float* __restrict__ ab2,
              u16* __restrict__ Tbv, u16* __restrict__ nTbk,
              u16* __restrict__ Aq, float* __restrict__ vecs,
              u16* __restrict__ Kt) {
  __shared__ u16 Kl[64][136], Ql[64][136];
  __shared__ float Gk[4096], Gq[4096];
  __shared__ float clL[64], laL[64], bL[64], gpL[64];
  const int unit = blockIdx.x;
  const int bh = unit >> 5, c = unit & 31;
  const int t = threadIdx.x;
  const int wv = t >> 6, lane = t & 63;
  const int l15 = lane & 15, l4 = lane >> 4;
  const u16* qb = qkv2 + ((size_t)bh * 2048 + c * 64) * 384;

  #pragma unroll
  for (int p = 0; p < 4; ++p) {
    int ld = p * 256 + t;
    int row = ld >> 4, c8 = (ld & 15) * 8;
    *(uint4*)&Kl[row][c8] = *(const uint4*)(qb + (size_t)row * 384 + c8);
    *(uint4*)&Ql[row][c8] = *(const uint4*)(qb + (size_t)row * 384 + 128 + c8);
  }
  if (wv == 0) {
    float2 abv = *(const float2*)(ab2 + ((size_t)bh * 2048 + c * 64 + lane) * 2);
    float la = log2f(abv.x);
    float cl = la;
    #pragma unroll
    for (int o = 1; o < 64; o <<= 1) {
      float nv = __shfl_up(cl, o, 64);
      if (lane >= o) cl += nv;
    }
    clL[lane] = cl; laL[lane] = la; bL[lane] = abv.y;
    gpL[lane] = exp2f(cl - la);
  }
  __syncthreads();

  {
    const int t0 = (wv >> 1) * 32, i0 = (wv & 1) * 32;
    f32x4 ak[2][2] = {}, aq[2][2] = {};
    #pragma unroll
    for (int ks = 0; ks < 4; ++ks) {
      short8 bk[2], Ka[2], Qa[2];
      #pragma unroll
      for (int n = 0; n < 2; ++n)
        bk[n] = *(const short8*)&Kl[i0 + n * 16 + l15][ks * 32 + l4 * 8];
      #pragma unroll
      for (int m = 0; m < 2; ++m) {
        Ka[m] = *(const short8*)&Kl[t0 + m * 16 + l15][ks * 32 + l4 * 8];
        Qa[m] = *(const short8*)&Ql[t0 + m * 16 + l15][ks * 32 + l4 * 8];
      }
      #pragma unroll
      for (int m = 0; m < 2; ++m)
        #pragma unroll
        for (int n = 0; n < 2; ++n) {
          ak[m][n] = MFMA16(Ka[m], bk[n], ak[m][n]);
          aq[m][n] = MFMA16(Qa[m], bk[n], aq[m][n]);
        }
    }
    #pragma unroll
    for (int m = 0; m < 2; ++m)
      #pragma unroll
      for (int n = 0; n < 2; ++n)
        #pragma unroll
        for (int e = 0; e < 4; ++e) {
          int row = t0 + m * 16 + l4 * 4 + e;
          int col = i0 + n * 16 + l15;
          Gk[row * 64 + col] = ak[m][n][e];
          Gq[row * 64 + col] = aq[m][n][e];
        }
  }
  __syncthreads();

  #pragma unroll
  for (int p = 0; p < 16; ++p) {
    int e = p * 256 + t; int tt = e >> 6, ii = e & 63;
    float lv = 0.f;
    if (ii < tt) lv = bL[tt] * Gk[e] * exp2f(clL[tt] - laL[tt] - clL[ii]);
    float av = (ii <= tt) ? Gq[e] * exp2f(clL[tt] - clL[ii]) : 0.f;
    Gk[e] = lv;
    Aq[(size_t)unit * 4096 + e] = f2bf(av);
  }
  __syncthreads();

  float X[64];
  if (t < 128) {
    #pragma unroll
    for (int r = 0; r < 64; ++r)
      X[r] = bL[r] * bf2f(qb[(size_t)r * 384 + 256 + t]);
  } else {
    int ck = t - 128;
    #pragma unroll
    for (int r = 0; r < 64; ++r)
      X[r] = -bL[r] * gpL[r] * bf2f(Kl[r][ck]);
  }
  #pragma unroll
  for (int i = 0; i < 63; ++i) {
    float xi = X[i];
    #pragma unroll
    for (int r = i + 1; r < 64; ++r)
      X[r] = fmaf(-Gk[r * 64 + i], xi, X[r]);
  }
  if (t < 128) {
    #pragma unroll
    for (int r = 0; r < 64; ++r)
      Tbv[(size_t)unit * 8192 + r * 128 + t] = f2bf(X[r]);
  } else {
    #pragma unroll
    for (int r = 0; r < 64; ++r)
      nTbk[(size_t)unit * 8192 + r * 128 + (t - 128)] = f2bf(X[r]);
  }
  if (t < 64) {
    vecs[(size_t)unit * 128 + t] = exp2f(clL[t]);
    vecs[(size_t)unit * 128 + 64 + t] = exp2f(clL[63] - clL[t]);
  }
  {
    int dk = t >> 1, tt0 = (t & 1) * 32;
    uint4 w[4];
    u16* wp = (u16*)w;
    #pragma unroll
    for (int j = 0; j < 32; ++j) wp[j] = Kl[tt0 + j][dk];
    uint4* dst = (uint4*)(Kt + (size_t)unit * 8192 + dk * 64 + tt0);
    dst[0] = w[0]; dst[1] = w[1]; dst[2] = w[2]; dst[3] = w[3];
  }
}

// ---------------- Phase B v2: 256 blocks (32 heads x 8 dv-slices of 16) ----------------
#define OFF_NT  0
#define OFF_AQ  8192
#define OFF_Q   12288
#define OFF_KT  20480
#define OFF_TBV 28672
#define STG_U16 29696

__global__ __launch_bounds__(256)
void k_chunkB(const u16* __restrict__ qkv2, const u16* __restrict__ Tbv,
              const u16* __restrict__ nTbk, const u16* __restrict__ Aq,
              const u16* __restrict__ Kt, const float* __restrict__ vecs,
              float* __restrict__ o) {
  __shared__ u16 stg[2][STG_U16];
  __shared__ float S[16 * 132];
  __shared__ u16 Ut[16 * 72], Utd[16 * 72];
  __shared__ float gdl[2][128];
  const int bid = blockIdx.x;
  const int xcd = bid & 7, within = bid >> 3;
  const int sl = within & 7, hgrp = within >> 3;
  const int bh = hgrp * 8 + xcd;
  const int dv0 = sl * 16;
  const int b = bh >> 4, h = bh & 15;
  const int t = threadIdx.x;
  const int wv = t >> 6, lane = t & 63;
  const int l15 = lane & 15, l4 = lane >> 4;
  const int t0 = wv * 16;
  const int dk0 = wv * 32;
  const u16* qbase = qkv2 + (size_t)bh * 2048 * 384;
  float* obase = o + (size_t)b * 2048 * 2048 + h * 128 + dv0;

  for (int p = t; p < 16 * 132; p += 256) S[p] = 0.f;

  auto stage = [&](int buf, int c) {
    u16* sb = &stg[buf][0];
    const size_t unit = (size_t)bh * 32 + c;
    const u16* tbk = nTbk + unit * 8192;
    const u16* aqp = Aq + unit * 4096;
    const u16* ktp = Kt + unit * 8192;
    const u16* tbv = Tbv + unit * 8192;
    const u16* qp  = qbase + (size_t)c * 64 * 384 + 128;
    #pragma unroll
    for (int r = 0; r < 4; ++r) {
      int f = r * 256 + t; int rr = f >> 4, c16 = f & 15;
      gld_lds16(tbk + rr * 128 + (c16 ^ (rr & 7)) * 8, sb + OFF_NT + (r * 256 + wv * 64) * 8);
    }
    #pragma unroll
    for (int r = 0; r < 2; ++r) {
      int f = r * 256 + t; int rr = f >> 3, c8 = f & 7;
      gld_lds16(aqp + rr * 64 + (c8 ^ (rr & 7)) * 8, sb + OFF_AQ + (r * 256 + wv * 64) * 8);
    }
    #pragma unroll
    for (int r = 0; r < 4; ++r) {
      int f = r * 256 + t; int rr = f >> 4, c16 = f & 15;
      gld_lds16(qp + rr * 384 + (c16 ^ (rr & 7)) * 8, sb + OFF_Q + (r * 256 + wv * 64) * 8);
    }
    #pragma unroll
    for (int r = 0; r < 4; ++r) {
      int f = r * 256 + t; int rr = f >> 3, c8 = f & 7;
      gld_lds16(ktp + rr * 64 + (c8 ^ (rr & 7)) * 8, sb + OFF_KT + (r * 256 + wv * 64) * 8);
    }
    if (t < 128)
      gld_lds16(tbv + (t >> 1) * 128 + dv0 + (t & 1) * 8, sb + OFF_TBV + wv * 64 * 8);
  };

  stage(0, 0);
  if (t < 128) gdl[0][t] = vecs[(size_t)bh * 32 * 128 + t];
  __syncthreads();

  for (int c = 0; c < 32; ++c) {
    const int buf = c & 1;
    const u16* sb = &stg[buf][0];
    float vnext = 0.f;
    if (c + 1 < 32) {
      stage(buf ^ 1, c + 1);
      if (t < 128) vnext = vecs[((size_t)bh * 32 + c + 1) * 128 + t];
    }

    f32x4 acc1 = {}, acc2 = {};
    #pragma unroll
    for (int e = 0; e < 4; ++e)
      acc1[e] = bf2f(sb[OFF_TBV + (t0 + l4 * 4 + e) * 16 + l15]);
    #pragma unroll
    for (int ks = 0; ks < 4; ++ks) {
      short8 bhi, blo;
      {
        const float* srow = &S[l15 * 132 + ks * 32 + l4 * 8];
        float4 s0 = *(const float4*)srow, s1 = *(const float4*)(srow + 4);
        float sv[8] = {s0.x, s0.y, s0.z, s0.w, s1.x, s1.y, s1.z, s1.w};
        #pragma unroll
        for (int j = 0; j < 8; ++j) {
          u16 hv = f2bf(sv[j]);
          bhi[j] = (short)hv;
          blo[j] = (short)f2bf(sv[j] - bf2f(hv));
        }
      }
      const int cx = ((ks * 4 + l4) ^ (l15 & 7)) * 8;
      short8 a1 = *(const short8*)&sb[OFF_NT + (t0 + l15) * 128 + cx];
      short8 a2 = *(const short8*)&sb[OFF_Q + (t0 + l15) * 128 + cx];
      acc1 = MFMA16(a1, bhi, acc1);
      acc1 = MFMA16(a1, blo, acc1);
      acc2 = MFMA16(a2, bhi, acc2);
      acc2 = MFMA16(a2, blo, acc2);
    }
    {
      u16 up[4], ud[4];
      #pragma unroll
      for (int e = 0; e < 4; ++e) {
        float uv = acc1[e];
        up[e] = f2bf(uv);
        ud[e] = f2bf(uv * gdl[buf][64 + t0 + l4 * 4 + e]);
      }
      int ux = l15 * 72 + t0 + l4 * 4;
      *(u32*)&Ut[ux]      = (u32)up[0] | ((u32)up[1] << 16);
      *(u32*)&Ut[ux + 2]  = (u32)up[2] | ((u32)up[3] << 16);
      *(u32*)&Utd[ux]     = (u32)ud[0] | ((u32)ud[1] << 16);
      *(u32*)&Utd[ux + 2] = (u32)ud[2] | ((u32)ud[3] << 16);
    }
    asm volatile("s_waitcnt lgkmcnt(0)" ::: "memory");
    __builtin_amdgcn_s_barrier();
    __builtin_amdgcn_sched_barrier(0);

    #pragma unroll
    for (int e = 0; e < 4; ++e) acc2[e] *= gdl[buf][t0 + l4 * 4 + e];
    #pragma unroll
    for (int ks = 0; ks < 2; ++ks) {
      const int cx = ((ks * 4 + l4) ^ (l15 & 7)) * 8;
      short8 af = *(const short8*)&sb[OFF_AQ + (t0 + l15) * 64 + cx];
      short8 bf_ = *(const short8*)&Ut[l15 * 72 + ks * 32 + l4 * 8];
      acc2 = MFMA16(af, bf_, acc2);
    }
    #pragma unroll
    for (int e = 0; e < 4; ++e)
      obase[(size_t)(c * 64 + t0 + l4 * 4 + e) * 2048 + l15] = acc2[e];

    f32x4 acc3[2] = {};
    #pragma unroll
    for (int ks = 0; ks < 2; ++ks) {
      short8 a3 = *(const short8*)&Utd[l15 * 72 + ks * 32 + l4 * 8];
      #pragma unroll
      for (int n = 0; n < 2; ++n) {
        const int kr = dk0 + n * 16 + l15;
        const int cx = ((ks * 4 + l4) ^ (l15 & 7)) * 8;
        short8 b3 = *(const short8*)&sb[OFF_KT + kr * 64 + cx];
        acc3[n] = MFMA16(a3, b3, acc3[n]);
      }
    }
    float gtot = gdl[buf][63];
    #pragma unroll
    for (int n = 0; n < 2; ++n)
      #pragma unroll
      for (int e = 0; e < 4; ++e) {
        float* sp = &S[(l4 * 4 + e) * 132 + dk0 + n * 16 + l15];
        *sp = gtot * *sp + acc3[n][e];
      }
    if (c + 1 < 32 && t < 128) gdl[buf ^ 1][t] = vnext;
    __syncthreads();
  }
}

// ---------------- LayerNorm(D) + sigmoid-gate, write bf16 ----------------
__global__ void k_lng(const float* __restrict__ o, const u16* __restrict__ projG,
                      const float* __restrict__ ln_w, const float* __restrict__ ln_b,
                      u16* __restrict__ og) {
  int gidx = blockIdx.x * 4 + (threadIdx.x >> 6);
  int lane = threadIdx.x & 63;
  int rrow = gidx >> 4, h = gidx & 15;
  const float* op = o + (size_t)rrow * 2048 + h * 128;
  float2 x2 = *(const float2*)(op + lane * 2);
  float sum = x2.x + x2.y, sq = x2.x * x2.x + x2.y * x2.y;
  #pragma unroll
  for (int m = 1; m < 64; m <<= 1) {
    sum += __shfl_xor(sum, m, 64);
    sq  += __shfl_xor(sq, m, 64);
  }
  float mu = sum * (1.f / 128.f);
  float var = sq * (1.f / 128.f) - mu * mu;
  float rs = 1.0f / sqrtf(var + 1e-5f);
  u32 gu = *(const u32*)(projG + (size_t)rrow * 2048 + h * 128 + lane * 2);
  float g0 = sigm(bflo(gu)), g1 = sigm(bfhi(gu));
  int d0 = lane * 2;
  float y0 = ((x2.x - mu) * rs * ln_w[d0] + ln_b[d0]) * g0;
  float y1 = ((x2.y - mu) * rs * ln_w[d0 + 1] + ln_b[d0 + 1]) * g1;
  *(u32*)(og + (size_t)rrow * 2048 + h * 128 + d0) = (u32)f2bf(y0) | ((u32)f2bf(y1) << 16);
}

extern "C" void kernel_launch(void* const* d_in, const int* in_sizes, int n_in,
                              void* d_out, int out_size, void* d_ws, size_t ws_size,
                              hipStream_t stream) {
  const float* x   = (const float*)d_in[0];
  const float* Wq  = (const float*)d_in[1];
  const float* Wk  = (const float*)d_in[2];
  const float* Wv  = (const float*)d_in[3];
  const float* Wa  = (const float*)d_in[4];
  const float* ba  = (const float*)d_in[5];
  const float* Wb  = (const float*)d_in[6];
  const float* bb  = (const float*)d_in[7];
  const float* Wg  = (const float*)d_in[8];
  const float* Wo  = (const float*)d_in[9];
  const float* qcw = (const float*)d_in[10];
  const float* qcb = (const float*)d_in[11];
  const float* kcw = (const float*)d_in[12];
  const float* kcb = (const float*)d_in[13];
  const float* vcw = (const float*)d_in[14];
  const float* vcb = (const float*)d_in[15];
  const float* lnw = (const float*)d_in[16];
  const float* lnb = (const float*)d_in[17];
  float* out = (float*)d_out;

  if (ws_size < 168820736ull) return;  // canary
  char* ws = (char*)d_ws;
  u16*   xb   = (u16*)(ws);
  u16*   Kt   = (u16*)(ws);
  u16*   og   = (u16*)(ws);
  u16*   Wt   = (u16*)(ws + 16777216);
  u16*   Wot  = (u16*)(ws + 16777216);
  u16*   Tbv  = (u16*)(ws + 25165824);
  u16*   Aq   = (u16*)(ws + 41943040);
  u16*   pQKV = (u16*)(ws + 50331648);
  float* oB   = (float*)(ws + 50331648);
  u16*   nTbk = (u16*)(ws + 83886080);
  u16*   pG   = (u16*)(ws + 100663296);
  u16*   qkv2 = (u16*)(ws + 117440512);
  float* ab2  = (float*)(ws + 167772160);
  float* vecs = (float*)(ws + 168296448);

  k_cvt_x<<<4096, 256, 0, stream>>>(x, xb);
  k_tconv4<<<dim3(64, 64, 4), 256, 0, stream>>>(Wq, Wk, Wv, Wg, Wt);
  k_ab<<<512, 256, 0, stream>>>(x, Wa, ba, Wb, bb, ab2);

  // fused QKVG projection: [4096 x 2048] @ [2048 x 8192] -> bf16 split (BK=32, 2 blocks/CU)
  k_gemm8<1><<<dim3(32, 16), 512, 0, stream>>>(xb, Wt, pQKV, pG);
  k_tconv<<<dim3(64, 64), 256, 0, stream>>>(Wo, Wot);
  k_conv<<<24576, 256, 0, stream>>>(pQKV, qcw, qcb, kcw, kcb, vcw, vcb, qkv2);
  k_chunkA<<<1024, 256, 0, stream>>>(qkv2, ab2, Tbv, nTbk, Aq, vecs, Kt);
  k_chunkB<<<256, 256, 0, stream>>>(qkv2, Tbv, nTbk, Aq, Kt, vecs, oB);
  k_lng<<<16384, 256, 0, stream>>>(oB, pG, lnw, lnb, og);
  k_gemm<0><<<dim3(16, 32), 256, 0, stream>>>(og, Wot, out, nullptr, 2048);
}

// Round 12
// 410.809 us; speedup vs baseline: 1.1482x; 1.1463x over previous
//
#include <hip/hip_runtime.h>
#include <math.h>
#include <stdint.h>

typedef unsigned short u16;
typedef unsigned int u32;
typedef __attribute__((ext_vector_type(8))) short short8;
typedef __attribute__((ext_vector_type(4))) float f32x4;

#define MFMA16(a, b, c) __builtin_amdgcn_mfma_f32_16x16x32_bf16(a, b, c, 0, 0, 0)

__device__ __forceinline__ u16 f2bf(float f) {
  union { float f; u32 u; } v; v.f = f;
  return (u16)((v.u + 0x7FFFu + ((v.u >> 16) & 1u)) >> 16);
}
__device__ __forceinline__ float bf2f(u16 h) {
  union { u32 u; float f; } v; v.u = ((u32)h) << 16; return v.f;
}
__device__ __forceinline__ float bflo(u32 p) {
  union { u32 u; float f; } v; v.u = p << 16; return v.f;
}
__device__ __forceinline__ float bfhi(u32 p) {
  union { u32 u; float f; } v; v.u = p & 0xffff0000u; return v.f;
}
__device__ __forceinline__ float sigm(float x) { return 1.f / (1.f + expf(-x)); }

// ---------------- x -> bf16 ----------------
__global__ void k_cvt_x(const float* __restrict__ x, u16* __restrict__ xb) {
  int i = (blockIdx.x * 256 + threadIdx.x) * 8;
  float4 a = *(const float4*)(x + i);
  float4 b = *(const float4*)(x + i + 4);
  uint4 p;
  p.x = (u32)f2bf(a.x) | ((u32)f2bf(a.y) << 16);
  p.y = (u32)f2bf(a.z) | ((u32)f2bf(a.w) << 16);
  p.z = (u32)f2bf(b.x) | ((u32)f2bf(b.y) << 16);
  p.w = (u32)f2bf(b.z) | ((u32)f2bf(b.w) << 16);
  *(uint4*)(xb + i) = p;
}

// ---------------- 4x W transpose: [K][N] f32 -> [N][K] bf16 ----------------
__global__ void k_tconv4(const float* __restrict__ W0, const float* __restrict__ W1,
                         const float* __restrict__ W2, const float* __restrict__ W3,
                         u16* __restrict__ Wt) {
  __shared__ float tile[32][33];
  int z = blockIdx.z;
  const float* W = (z == 0) ? W0 : (z == 1) ? W1 : (z == 2) ? W2 : W3;
  u16* dst = Wt + (size_t)z * 2048 * 2048;
  int n0 = blockIdx.x * 32, k0 = blockIdx.y * 32;
  int tc = threadIdx.x & 31, tr = threadIdx.x >> 5;
  #pragma unroll
  for (int p = 0; p < 4; ++p) {
    int k = k0 + p * 8 + tr;
    tile[p * 8 + tr][tc] = W[(size_t)k * 2048 + n0 + tc];
  }
  __syncthreads();
  #pragma unroll
  for (int p = 0; p < 4; ++p) {
    int n = n0 + p * 8 + tr;
    dst[(size_t)n * 2048 + k0 + tc] = f2bf(tile[tc][p * 8 + tr]);
  }
}

__global__ void k_tconv(const float* __restrict__ W, u16* __restrict__ Wt) {
  __shared__ float tile[32][33];
  int n0 = blockIdx.x * 32, k0 = blockIdx.y * 32;
  int tc = threadIdx.x & 31, tr = threadIdx.x >> 5;
  #pragma unroll
  for (int p = 0; p < 4; ++p) {
    int k = k0 + p * 8 + tr;
    tile[p * 8 + tr][tc] = W[(size_t)k * 2048 + n0 + tc];
  }
  __syncthreads();
  #pragma unroll
  for (int p = 0; p < 4; ++p) {
    int n = n0 + p * 8 + tr;
    Wt[(size_t)n * 2048 + k0 + tc] = f2bf(tile[tc][p * 8 + tr]);
  }
}

// ---------------- alpha/beta GEMV, LDS-tiled f32 ----------------
__global__ __launch_bounds__(256)
void k_ab(const float* __restrict__ x, const float* __restrict__ Wa,
          const float* __restrict__ ba, const float* __restrict__ Wb,
          const float* __restrict__ bb, float* __restrict__ ab2) {
  __shared__ float Wl[128 * 32];
  __shared__ float xl[8][128];
  const int t = threadIdx.x;
  const int lr = t >> 5, c = t & 31;
  const int r0 = blockIdx.x * 8;
  const int ch = c & 15;
  float acc = 0.f;
  for (int kt = 0; kt < 16; ++kt) {
    #pragma unroll
    for (int i = 0; i < 16; ++i) {
      int idx = i * 256 + t;
      int kk = idx >> 5, cc = idx & 31;
      const float* Ws = (cc < 16) ? Wa : Wb;
      Wl[kk * 32 + cc] = Ws[(kt * 128 + kk) * 16 + (cc & 15)];
    }
    #pragma unroll
    for (int i = 0; i < 4; ++i) {
      int idx = i * 256 + t;
      int rr = idx >> 7, kk = idx & 127;
      xl[rr][kk] = x[(size_t)(r0 + rr) * 2048 + kt * 128 + kk];
    }
    __syncthreads();
    #pragma unroll
    for (int kk = 0; kk < 128; kk += 4) {
      float2 x01 = *(const float2*)&xl[lr][kk];
      float2 x23 = *(const float2*)&xl[lr][kk + 2];
      acc += x01.x * Wl[(kk + 0) * 32 + c] + x01.y * Wl[(kk + 1) * 32 + c]
           + x23.x * Wl[(kk + 2) * 32 + c] + x23.y * Wl[(kk + 3) * 32 + c];
    }
    __syncthreads();
  }
  acc += (c < 16) ? ba[ch] : bb[ch];
  float sg = sigm(acc);
  int rowi = r0 + lr;
  int b = rowi >> 11, s = rowi & 2047;
  size_t base = ((size_t)(b * 16 + ch) * 2048 + s) * 2;
  if (c < 16) ab2[base + 0] = sg;
  else        ab2[base + 1] = sg;
}

__device__ __forceinline__ void gld_lds16(const u16* g, u16* l) {
  __builtin_amdgcn_global_load_lds((const __attribute__((address_space(1))) void*)g,
                                   (__attribute__((address_space(3))) void*)l, 16, 0, 0);
}

// ---------------- 128x128 GEMM with T2 swizzle (out-projection) ----------------
template <int MODE>
__global__ void k_gemm(const u16* __restrict__ A, const u16* __restrict__ Bw,
                       void* C0, void* C1, int Kd) {
  __shared__ u16 As[2][128 * 32];
  __shared__ u16 Bs[2][128 * 32];
  const int t = threadIdx.x;
  const int lane = t & 63, wv = t >> 6;
  const int wr = wv >> 1, wc = wv & 1;
  const int m0 = blockIdx.y * 128, n0 = blockIdx.x * 128;
  f32x4 acc[4][4] = {};
  const int NT = Kd / 32;

  auto stage = [&](int buf, int kt) {
    #pragma unroll
    for (int i = 0; i < 2; ++i) {
      int li = i * 256 + t;
      int row = li >> 2, kc = li & 3;
      int kcs = kc ^ ((row >> 1) & 3);
      const u16* ga = A + (size_t)(m0 + row) * Kd + kt * 32 + kcs * 8;
      gld_lds16(ga, &As[buf][(i * 256 + wv * 64) * 8]);
      const u16* gb = Bw + (size_t)(n0 + row) * Kd + kt * 32 + kcs * 8;
      gld_lds16(gb, &Bs[buf][(i * 256 + wv * 64) * 8]);
    }
  };

  stage(0, 0);
  __syncthreads();
  int buf = 0;
  const int l15 = lane & 15, l4 = lane >> 4;
  for (int kt = 0; kt < NT; ++kt) {
    if (kt + 1 < NT) stage(buf ^ 1, kt + 1);
    short8 af[4], bfr[4];
    #pragma unroll
    for (int m = 0; m < 4; ++m) {
      int row = wr * 64 + m * 16 + l15;
      int g = l4 ^ ((row >> 1) & 3);
      af[m] = *(const short8*)&As[buf][row * 32 + g * 8];
    }
    #pragma unroll
    for (int n = 0; n < 4; ++n) {
      int row = wc * 64 + n * 16 + l15;
      int g = l4 ^ ((row >> 1) & 3);
      bfr[n] = *(const short8*)&Bs[buf][row * 32 + g * 8];
    }
    #pragma unroll
    for (int m = 0; m < 4; ++m)
      #pragma unroll
      for (int n = 0; n < 4; ++n)
        acc[m][n] = MFMA16(af[m], bfr[n], acc[m][n]);
    __syncthreads();
    buf ^= 1;
  }
  #pragma unroll
  for (int m = 0; m < 4; ++m)
    #pragma unroll
    for (int n = 0; n < 4; ++n)
      #pragma unroll
      for (int e = 0; e < 4; ++e) {
        int row = m0 + wr * 64 + m * 16 + l4 * 4 + e;
        int col = n0 + wc * 64 + n * 16 + l15;
        if (MODE == 0) {
          ((float*)C0)[(size_t)row * 2048 + col] = acc[m][n][e];
        } else {
          u16 vb = f2bf(acc[m][n][e]);
          if (n0 < 6144) ((u16*)C0)[(size_t)row * 6144 + col] = vb;
          else           ((u16*)C1)[(size_t)row * 2048 + (col - 6144)] = vb;
        }
      }
}

// ---------------- 256x256 GEMM, 2-region counted-vmcnt schedule (QKVG) ----------------
template <int MODE>
__global__ __launch_bounds__(512)
void k_gemm8(const u16* __restrict__ A, const u16* __restrict__ Bw,
             void* C0, void* C1) {
  __shared__ u16 lds[65536];
  const int t = threadIdx.x;
  const int w = t >> 6, lane = t & 63;
  const int l15 = lane & 15, l4 = lane >> 4;
  const int wm = w >> 2, wn = w & 3;
  const int m0 = blockIdx.y * 256, n0 = blockIdx.x * 256;

  f32x4 acc[8][4] = {};
  short8 a[4][2], b[4][2];

  auto stageHalf = [&](int buf, int kt, int mat, int half) {
    const u16* src = mat ? Bw : A;
    const int row0 = (mat ? n0 : m0) + half * 128;
    u16* dst0 = &lds[mat * 32768 + (buf * 2 + half) * 8192 + w * 1024];
    #pragma unroll
    for (int i = 0; i < 2; ++i) {
      int f = w * 128 + i * 64 + lane;
      int rr = f >> 3, g = f & 7;
      const u16* ga = src + (size_t)(row0 + rr) * 2048 + kt * 64 + ((g ^ (rr & 7)) << 3);
      gld_lds16(ga, dst0 + i * 512);
    }
  };
  auto rdA = [&](int buf, int mq, int ks) {
    int row = wm * 64 + (mq & 3) * 16 + l15;
    int g = (l4 + ks * 4) ^ (row & 7);
    return *(const short8*)&lds[(buf * 2 + (mq >> 2)) * 8192 + row * 64 + g * 8];
  };
  auto rdB = [&](int buf, int n, int ks) {
    int row = wn * 32 + (n & 1) * 16 + l15;
    int g = (l4 + ks * 4) ^ (row & 7);
    return *(const short8*)&lds[32768 + (buf * 2 + (n >> 1)) * 8192 + row * 64 + g * 8];
  };

  // prologue: K-tile 0 in issue order Ah0,Bh0,Bh1,Ah1; full drain
  stageHalf(0, 0, 0, 0); stageHalf(0, 0, 1, 0);
  stageHalf(0, 0, 1, 1); stageHalf(0, 0, 0, 1);
  asm volatile("s_waitcnt vmcnt(0)" ::: "memory");
  __builtin_amdgcn_s_barrier();
  __builtin_amdgcn_sched_barrier(0);

  for (int kt = 0; kt < 32; ++kt) {
    const int bufc = kt & 1, bufn = bufc ^ 1;
    const int ktn = (kt + 1 < 32) ? kt + 1 : 31;   // last iter: dummy re-stage

    // ---- region 1: m-lo x all-n ----
    stageHalf(bufn, ktn, 0, 0);   // Ah0'
    stageHalf(bufn, ktn, 1, 0);   // Bh0'
    stageHalf(bufn, ktn, 1, 1);   // Bh1'
    #pragma unroll
    for (int mq = 0; mq < 4; ++mq) { a[mq][0] = rdA(bufc, mq, 0); a[mq][1] = rdA(bufc, mq, 1); }
    #pragma unroll
    for (int n = 0; n < 4; ++n) { b[n][0] = rdB(bufc, n, 0); b[n][1] = rdB(bufc, n, 1); }
    __builtin_amdgcn_s_setprio(1);
    #pragma unroll
    for (int mq = 0; mq < 4; ++mq)
      #pragma unroll
      for (int n = 0; n < 4; ++n) {
        acc[mq][n] = MFMA16(a[mq][0], b[n][0], acc[mq][n]);
        acc[mq][n] = MFMA16(a[mq][1], b[n][1], acc[mq][n]);
      }
    __builtin_amdgcn_s_setprio(0);
    asm volatile("s_waitcnt vmcnt(6)" ::: "memory");   // Ah1(kt) landed
    __builtin_amdgcn_s_barrier();
    __builtin_amdgcn_sched_barrier(0);

    // ---- region 2: m-hi x all-n ----
    stageHalf(bufn, ktn, 0, 1);   // Ah1'
    #pragma unroll
    for (int mq = 0; mq < 4; ++mq) { a[mq][0] = rdA(bufc, mq + 4, 0); a[mq][1] = rdA(bufc, mq + 4, 1); }
    __builtin_amdgcn_s_setprio(1);
    #pragma unroll
    for (int mq = 0; mq < 4; ++mq)
      #pragma unroll
      for (int n = 0; n < 4; ++n) {
        acc[mq + 4][n] = MFMA16(a[mq][0], b[n][0], acc[mq + 4][n]);
        acc[mq + 4][n] = MFMA16(a[mq][1], b[n][1], acc[mq + 4][n]);
      }
    __builtin_amdgcn_s_setprio(0);
    asm volatile("s_waitcnt vmcnt(2)" ::: "memory");   // Ah0',Bh0',Bh1'(kt+1) landed
    __builtin_amdgcn_s_barrier();
    __builtin_amdgcn_sched_barrier(0);
  }

  const bool toG = (MODE == 1) && (n0 >= 6144);
  #pragma unroll
  for (int mq = 0; mq < 8; ++mq) {
    int row = m0 + (mq >> 2) * 128 + wm * 64 + (mq & 3) * 16 + l4 * 4;
    #pragma unroll
    for (int n = 0; n < 4; ++n) {
      int col = n0 + (n >> 1) * 128 + wn * 32 + (n & 1) * 16 + l15;
      #pragma unroll
      for (int e = 0; e < 4; ++e) {
        if (MODE == 0) {
          ((float*)C0)[(size_t)(row + e) * 2048 + col] = acc[mq][n][e];
        } else {
          u16 vb = f2bf(acc[mq][n][e]);
          if (!toG) ((u16*)C0)[(size_t)(row + e) * 6144 + col] = vb;
          else      ((u16*)C1)[(size_t)(row + e) * 2048 + (col - 6144)] = vb;
        }
      }
    }
  }
}

// ---------------- causal depthwise conv v2: 4 s-positions/thread, single-pass ----------------
__global__ __launch_bounds__(256)
void k_conv(const u16* __restrict__ projQKV,
            const float* __restrict__ qcw, const float* __restrict__ qcb,
            const float* __restrict__ kcw, const float* __restrict__ kcb,
            const float* __restrict__ vcw, const float* __restrict__ vcb,
            u16* __restrict__ qkv2) {
  int idx = blockIdx.x * 256 + threadIdx.x;   // 2 b * 512 sgroups * 1536 cquads
  int cq = idx % 1536, rg = idx / 1536;
  int c = cq * 4;
  int b = rg >> 9, sg = rg & 511;
  int s0 = sg * 4;
  int type = c >> 11;             // 0=q,1=k,2=v
  int ch = c & 2047;
  int h = ch >> 7, d = ch & 127;
  const float* cw; const float* cb;
  if (type == 0)      { cw = qcw; cb = qcb; }
  else if (type == 1) { cw = kcw; cb = kcb; }
  else                { cw = vcw; cb = vcb; }
  float wch[4][4];
  #pragma unroll
  for (int u = 0; u < 4; ++u) {
    float4 wv = *(const float4*)(cw + (ch + u) * 4);
    wch[u][0] = wv.x; wch[u][1] = wv.y; wch[u][2] = wv.z; wch[u][3] = wv.w;
  }
  float4 bv = *(const float4*)(cb + ch);
  // window rows s0-3 .. s0+3
  float win[7][4];
  #pragma unroll
  for (int j = 0; j < 7; ++j) {
    int s = s0 - 3 + j;
    if (s < 0) { win[j][0] = win[j][1] = win[j][2] = win[j][3] = 0.f; continue; }
    const u16* p = projQKV + (size_t)(b * 2048 + s) * 6144 + c;
    u32 pa = *(const u32*)p;
    u32 pb2 = *(const u32*)(p + 2);
    win[j][0] = bflo(pa); win[j][1] = bfhi(pa);
    win[j][2] = bflo(pb2); win[j][3] = bfhi(pb2);
  }
  int off = (type == 1 ? 0 : (type == 0 ? 128 : 256)) + d;
  u16* dst0 = qkv2 + ((size_t)(b * 16 + h) * 2048 + s0) * 384 + off;
  #pragma unroll
  for (int i = 0; i < 4; ++i) {
    float a0 = bv.x, a1 = bv.y, a2 = bv.z, a3 = bv.w;
    #pragma unroll
    for (int j = 0; j < 4; ++j) {
      a0 += win[i + j][0] * wch[0][j];
      a1 += win[i + j][1] * wch[1][j];
      a2 += win[i + j][2] * wch[2][j];
      a3 += win[i + j][3] * wch[3][j];
    }
    float o0 = a0 * sigm(a0), o1 = a1 * sigm(a1);
    float o2 = a2 * sigm(a2), o3 = a3 * sigm(a3);
    if (type == 1) {
      o0 *= 0.08838834764831845f; o1 *= 0.08838834764831845f;
      o2 *= 0.08838834764831845f; o3 *= 0.08838834764831845f;
    }
    u16* dst = dst0 + (size_t)i * 384;
    *(u32*)dst       = (u32)f2bf(o0) | ((u32)f2bf(o1) << 16);
    *(u32*)(dst + 2) = (u32)f2bf(o2) | ((u32)f2bf(o3) << 16);
  }
}

// ---------------- Phase A: per-(head,chunk) WY precompute ----------------
__global__ __launch_bounds__(256)
void k_chunkA(const u16* __restrict__ qkv2, const float* __restrict__ ab2,
              u16* __restrict__ Tbv, u16* __restrict__ nTbk,
              u16* __restrict__ Aq, float* __restrict__ vecs,
              u16* __restrict__ Kt) {
  __shared__ u16 Kl[64][136], Ql[64][136];
  __shared__ float Gk[4096], Gq[4096];
  __shared__ float clL[64], laL[64], bL[64], gpL[64];
  const int unit = blockIdx.x;
  const int bh = unit >> 5, c = unit & 31;
  const int t = threadIdx.x;
  const int wv = t >> 6, lane = t & 63;
  const int l15 = lane & 15, l4 = lane >> 4;
  const u16* qb = qkv2 + ((size_t)bh * 2048 + c * 64) * 384;

  #pragma unroll
  for (int p = 0; p < 4; ++p) {
    int ld = p * 256 + t;
    int row = ld >> 4, c8 = (ld & 15) * 8;
    *(uint4*)&Kl[row][c8] = *(const uint4*)(qb + (size_t)row * 384 + c8);
    *(uint4*)&Ql[row][c8] = *(const uint4*)(qb + (size_t)row * 384 + 128 + c8);
  }
  if (wv == 0) {
    float2 abv = *(const float2*)(ab2 + ((size_t)bh * 2048 + c * 64 + lane) * 2);
    float la = log2f(abv.x);
    float cl = la;
    #pragma unroll
    for (int o = 1; o < 64; o <<= 1) {
      float nv = __shfl_up(cl, o, 64);
      if (lane >= o) cl += nv;
    }
    clL[lane] = cl; laL[lane] = la; bL[lane] = abv.y;
    gpL[lane] = exp2f(cl - la);
  }
  __syncthreads();

  {
    const int t0 = (wv >> 1) * 32, i0 = (wv & 1) * 32;
    f32x4 ak[2][2] = {}, aq[2][2] = {};
    #pragma unroll
    for (int ks = 0; ks < 4; ++ks) {
      short8 bk[2], Ka[2], Qa[2];
      #pragma unroll
      for (int n = 0; n < 2; ++n)
        bk[n] = *(const short8*)&Kl[i0 + n * 16 + l15][ks * 32 + l4 * 8];
      #pragma unroll
      for (int m = 0; m < 2; ++m) {
        Ka[m] = *(const short8*)&Kl[t0 + m * 16 + l15][ks * 32 + l4 * 8];
        Qa[m] = *(const short8*)&Ql[t0 + m * 16 + l15][ks * 32 + l4 * 8];
      }
      #pragma unroll
      for (int m = 0; m < 2; ++m)
        #pragma unroll
        for (int n = 0; n < 2; ++n) {
          ak[m][n] = MFMA16(Ka[m], bk[n], ak[m][n]);
          aq[m][n] = MFMA16(Qa[m], bk[n], aq[m][n]);
        }
    }
    #pragma unroll
    for (int m = 0; m < 2; ++m)
      #pragma unroll
      for (int n = 0; n < 2; ++n)
        #pragma unroll
        for (int e = 0; e < 4; ++e) {
          int row = t0 + m * 16 + l4 * 4 + e;
          int col = i0 + n * 16 + l15;
          Gk[row * 64 + col] = ak[m][n][e];
          Gq[row * 64 + col] = aq[m][n][e];
        }
  }
  __syncthreads();

  #pragma unroll
  for (int p = 0; p < 16; ++p) {
    int e = p * 256 + t; int tt = e >> 6, ii = e & 63;
    float lv = 0.f;
    if (ii < tt) lv = bL[tt] * Gk[e] * exp2f(clL[tt] - laL[tt] - clL[ii]);
    float av = (ii <= tt) ? Gq[e] * exp2f(clL[tt] - clL[ii]) : 0.f;
    Gk[e] = lv;
    Aq[(size_t)unit * 4096 + e] = f2bf(av);
  }
  __syncthreads();

  float X[64];
  if (t < 128) {
    #pragma unroll
    for (int r = 0; r < 64; ++r)
      X[r] = bL[r] * bf2f(qb[(size_t)r * 384 + 256 + t]);
  } else {
    int ck = t - 128;
    #pragma unroll
    for (int r = 0; r < 64; ++r)
      X[r] = -bL[r] * gpL[r] * bf2f(Kl[r][ck]);
  }
  #pragma unroll
  for (int i = 0; i < 63; ++i) {
    float xi = X[i];
    #pragma unroll
    for (int r = i + 1; r < 64; ++r)
      X[r] = fmaf(-Gk[r * 64 + i], xi, X[r]);
  }
  if (t < 128) {
    #pragma unroll
    for (int r = 0; r < 64; ++r)
      Tbv[(size_t)unit * 8192 + r * 128 + t] = f2bf(X[r]);
  } else {
    #pragma unroll
    for (int r = 0; r < 64; ++r)
      nTbk[(size_t)unit * 8192 + r * 128 + (t - 128)] = f2bf(X[r]);
  }
  if (t < 64) {
    vecs[(size_t)unit * 128 + t] = exp2f(clL[t]);
    vecs[(size_t)unit * 128 + 64 + t] = exp2f(clL[63] - clL[t]);
  }
  {
    int dk = t >> 1, tt0 = (t & 1) * 32;
    uint4 w[4];
    u16* wp = (u16*)w;
    #pragma unroll
    for (int j = 0; j < 32; ++j) wp[j] = Kl[tt0 + j][dk];
    uint4* dst = (uint4*)(Kt + (size_t)unit * 8192 + dk * 64 + tt0);
    dst[0] = w[0]; dst[1] = w[1]; dst[2] = w[2]; dst[3] = w[3];
  }
}

// ---------------- Phase B v2: 256 blocks (32 heads x 8 dv-slices of 16) ----------------
#define OFF_NT  0
#define OFF_AQ  8192
#define OFF_Q   12288
#define OFF_KT  20480
#define OFF_TBV 28672
#define STG_U16 29696

__global__ __launch_bounds__(256)
void k_chunkB(const u16* __restrict__ qkv2, const u16* __restrict__ Tbv,
              const u16* __restrict__ nTbk, const u16* __restrict__ Aq,
              const u16* __restrict__ Kt, const float* __restrict__ vecs,
              float* __restrict__ o) {
  __shared__ u16 stg[2][STG_U16];
  __shared__ float S[16 * 132];
  __shared__ u16 Ut[16 * 72], Utd[16 * 72];
  __shared__ float gdl[2][128];
  const int bid = blockIdx.x;
  const int xcd = bid & 7, within = bid >> 3;
  const int sl = within & 7, hgrp = within >> 3;
  const int bh = hgrp * 8 + xcd;
  const int dv0 = sl * 16;
  const int b = bh >> 4, h = bh & 15;
  const int t = threadIdx.x;
  const int wv = t >> 6, lane = t & 63;
  const int l15 = lane & 15, l4 = lane >> 4;
  const int t0 = wv * 16;
  const int dk0 = wv * 32;
  const u16* qbase = qkv2 + (size_t)bh * 2048 * 384;
  float* obase = o + (size_t)b * 2048 * 2048 + h * 128 + dv0;

  for (int p = t; p < 16 * 132; p += 256) S[p] = 0.f;

  auto stage = [&](int buf, int c) {
    u16* sb = &stg[buf][0];
    const size_t unit = (size_t)bh * 32 + c;
    const u16* tbk = nTbk + unit * 8192;
    const u16* aqp = Aq + unit * 4096;
    const u16* ktp = Kt + unit * 8192;
    const u16* tbv = Tbv + unit * 8192;
    const u16* qp  = qbase + (size_t)c * 64 * 384 + 128;
    #pragma unroll
    for (int r = 0; r < 4; ++r) {
      int f = r * 256 + t; int rr = f >> 4, c16 = f & 15;
      gld_lds16(tbk + rr * 128 + (c16 ^ (rr & 7)) * 8, sb + OFF_NT + (r * 256 + wv * 64) * 8);
    }
    #pragma unroll
    for (int r = 0; r < 2; ++r) {
      int f = r * 256 + t; int rr = f >> 3, c8 = f & 7;
      gld_lds16(aqp + rr * 64 + (c8 ^ (rr & 7)) * 8, sb + OFF_AQ + (r * 256 + wv * 64) * 8);
    }
    #pragma unroll
    for (int r = 0; r < 4; ++r) {
      int f = r * 256 + t; int rr = f >> 4, c16 = f & 15;
      gld_lds16(qp + rr * 384 + (c16 ^ (rr & 7)) * 8, sb + OFF_Q + (r * 256 + wv * 64) * 8);
    }
    #pragma unroll
    for (int r = 0; r < 4; ++r) {
      int f = r * 256 + t; int rr = f >> 3, c8 = f & 7;
      gld_lds16(ktp + rr * 64 + (c8 ^ (rr & 7)) * 8, sb + OFF_KT + (r * 256 + wv * 64) * 8);
    }
    if (t < 128)
      gld_lds16(tbv + (t >> 1) * 128 + dv0 + (t & 1) * 8, sb + OFF_TBV + wv * 64 * 8);
  };

  stage(0, 0);
  if (t < 128) gdl[0][t] = vecs[(size_t)bh * 32 * 128 + t];
  __syncthreads();

  for (int c = 0; c < 32; ++c) {
    const int buf = c & 1;
    const u16* sb = &stg[buf][0];
    float vnext = 0.f;
    if (c + 1 < 32) {
      stage(buf ^ 1, c + 1);
      if (t < 128) vnext = vecs[((size_t)bh * 32 + c + 1) * 128 + t];
    }

    f32x4 acc1 = {}, acc2 = {};
    #pragma unroll
    for (int e = 0; e < 4; ++e)
      acc1[e] = bf2f(sb[OFF_TBV + (t0 + l4 * 4 + e) * 16 + l15]);
    #pragma unroll
    for (int ks = 0; ks < 4; ++ks) {
      short8 bhi, blo;
      {
        const float* srow = &S[l15 * 132 + ks * 32 + l4 * 8];
        float4 s0 = *(const float4*)srow, s1 = *(const float4*)(srow + 4);
        float sv[8] = {s0.x, s0.y, s0.z, s0.w, s1.x, s1.y, s1.z, s1.w};
        #pragma unroll
        for (int j = 0; j < 8; ++j) {
          u16 hv = f2bf(sv[j]);
          bhi[j] = (short)hv;
          blo[j] = (short)f2bf(sv[j] - bf2f(hv));
        }
      }
      const int cx = ((ks * 4 + l4) ^ (l15 & 7)) * 8;
      short8 a1 = *(const short8*)&sb[OFF_NT + (t0 + l15) * 128 + cx];
      short8 a2 = *(const short8*)&sb[OFF_Q + (t0 + l15) * 128 + cx];
      acc1 = MFMA16(a1, bhi, acc1);
      acc1 = MFMA16(a1, blo, acc1);
      acc2 = MFMA16(a2, bhi, acc2);
      acc2 = MFMA16(a2, blo, acc2);
    }
    {
      u16 up[4], ud[4];
      #pragma unroll
      for (int e = 0; e < 4; ++e) {
        float uv = acc1[e];
        up[e] = f2bf(uv);
        ud[e] = f2bf(uv * gdl[buf][64 + t0 + l4 * 4 + e]);
      }
      int ux = l15 * 72 + t0 + l4 * 4;
      *(u32*)&Ut[ux]      = (u32)up[0] | ((u32)up[1] << 16);
      *(u32*)&Ut[ux + 2]  = (u32)up[2] | ((u32)up[3] << 16);
      *(u32*)&Utd[ux]     = (u32)ud[0] | ((u32)ud[1] << 16);
      *(u32*)&Utd[ux + 2] = (u32)ud[2] | ((u32)ud[3] << 16);
    }
    asm volatile("s_waitcnt lgkmcnt(0)" ::: "memory");
    __builtin_amdgcn_s_barrier();
    __builtin_amdgcn_sched_barrier(0);

    #pragma unroll
    for (int e = 0; e < 4; ++e) acc2[e] *= gdl[buf][t0 + l4 * 4 + e];
    #pragma unroll
    for (int ks = 0; ks < 2; ++ks) {
      const int cx = ((ks * 4 + l4) ^ (l15 & 7)) * 8;
      short8 af = *(const short8*)&sb[OFF_AQ + (t0 + l15) * 64 + cx];
      short8 bf_ = *(const short8*)&Ut[l15 * 72 + ks * 32 + l4 * 8];
      acc2 = MFMA16(af, bf_, acc2);
    }
    #pragma unroll
    for (int e = 0; e < 4; ++e)
      obase[(size_t)(c * 64 + t0 + l4 * 4 + e) * 2048 + l15] = acc2[e];

    f32x4 acc3[2] = {};
    #pragma unroll
    for (int ks = 0; ks < 2; ++ks) {
      short8 a3 = *(const short8*)&Utd[l15 * 72 + ks * 32 + l4 * 8];
      #pragma unroll
      for (int n = 0; n < 2; ++n) {
        const int kr = dk0 + n * 16 + l15;
        const int cx = ((ks * 4 + l4) ^ (l15 & 7)) * 8;
        short8 b3 = *(const short8*)&sb[OFF_KT + kr * 64 + cx];
        acc3[n] = MFMA16(a3, b3, acc3[n]);
      }
    }
    float gtot = gdl[buf][63];
    #pragma unroll
    for (int n = 0; n < 2; ++n)
      #pragma unroll
      for (int e = 0; e < 4; ++e) {
        float* sp = &S[(l4 * 4 + e) * 132 + dk0 + n * 16 + l15];
        *sp = gtot * *sp + acc3[n][e];
      }
    if (c + 1 < 32 && t < 128) gdl[buf ^ 1][t] = vnext;
    __syncthreads();
  }
}

// ---------------- LayerNorm(D) + sigmoid-gate, write bf16 ----------------
__global__ void k_lng(const float* __restrict__ o, const u16* __restrict__ projG,
                      const float* __restrict__ ln_w, const float* __restrict__ ln_b,
                      u16* __restrict__ og) {
  int gidx = blockIdx.x * 4 + (threadIdx.x >> 6);
  int lane = threadIdx.x & 63;
  int rrow = gidx >> 4, h = gidx & 15;
  const float* op = o + (size_t)rrow * 2048 + h * 128;
  float2 x2 = *(const float2*)(op + lane * 2);
  float sum = x2.x + x2.y, sq = x2.x * x2.x + x2.y * x2.y;
  #pragma unroll
  for (int m = 1; m < 64; m <<= 1) {
    sum += __shfl_xor(sum, m, 64);
    sq  += __shfl_xor(sq, m, 64);
  }
  float mu = sum * (1.f / 128.f);
  float var = sq * (1.f / 128.f) - mu * mu;
  float rs = 1.0f / sqrtf(var + 1e-5f);
  u32 gu = *(const u32*)(projG + (size_t)rrow * 2048 + h * 128 + lane * 2);
  float g0 = sigm(bflo(gu)), g1 = sigm(bfhi(gu));
  int d0 = lane * 2;
  float y0 = ((x2.x - mu) * rs * ln_w[d0] + ln_b[d0]) * g0;
  float y1 = ((x2.y - mu) * rs * ln_w[d0 + 1] + ln_b[d0 + 1]) * g1;
  *(u32*)(og + (size_t)rrow * 2048 + h * 128 + d0) = (u32)f2bf(y0) | ((u32)f2bf(y1) << 16);
}

extern "C" void kernel_launch(void* const* d_in, const int* in_sizes, int n_in,
                              void* d_out, int out_size, void* d_ws, size_t ws_size,
                              hipStream_t stream) {
  const float* x   = (const float*)d_in[0];
  const float* Wq  = (const float*)d_in[1];
  const float* Wk  = (const float*)d_in[2];
  const float* Wv  = (const float*)d_in[3];
  const float* Wa  = (const float*)d_in[4];
  const float* ba  = (const float*)d_in[5];
  const float* Wb  = (const float*)d_in[6];
  const float* bb  = (const float*)d_in[7];
  const float* Wg  = (const float*)d_in[8];
  const float* Wo  = (const float*)d_in[9];
  const float* qcw = (const float*)d_in[10];
  const float* qcb = (const float*)d_in[11];
  const float* kcw = (const float*)d_in[12];
  const float* kcb = (const float*)d_in[13];
  const float* vcw = (const float*)d_in[14];
  const float* vcb = (const float*)d_in[15];
  const float* lnw = (const float*)d_in[16];
  const float* lnb = (const float*)d_in[17];
  float* out = (float*)d_out;

  if (ws_size < 168820736ull) return;  // canary
  char* ws = (char*)d_ws;
  u16*   xb   = (u16*)(ws);
  u16*   Kt   = (u16*)(ws);
  u16*   og   = (u16*)(ws);
  u16*   Wt   = (u16*)(ws + 16777216);
  u16*   Wot  = (u16*)(ws + 16777216);
  u16*   Tbv  = (u16*)(ws + 25165824);
  u16*   Aq   = (u16*)(ws + 41943040);
  u16*   pQKV = (u16*)(ws + 50331648);
  float* oB   = (float*)(ws + 50331648);
  u16*   nTbk = (u16*)(ws + 83886080);
  u16*   pG   = (u16*)(ws + 100663296);
  u16*   qkv2 = (u16*)(ws + 117440512);
  float* ab2  = (float*)(ws + 167772160);
  float* vecs = (float*)(ws + 168296448);

  k_cvt_x<<<4096, 256, 0, stream>>>(x, xb);
  k_tconv4<<<dim3(64, 64, 4), 256, 0, stream>>>(Wq, Wk, Wv, Wg, Wt);
  k_ab<<<512, 256, 0, stream>>>(x, Wa, ba, Wb, bb, ab2);

  // fused QKVG projection: [4096 x 2048] @ [2048 x 8192] -> bf16 split (2-region)
  k_gemm8<1><<<dim3(32, 16), 512, 0, stream>>>(xb, Wt, pQKV, pG);
  k_tconv<<<dim3(64, 64), 256, 0, stream>>>(Wo, Wot);
  k_conv<<<6144, 256, 0, stream>>>(pQKV, qcw, qcb, kcw, kcb, vcw, vcb, qkv2);
  k_chunkA<<<1024, 256, 0, stream>>>(qkv2, ab2, Tbv, nTbk, Aq, vecs, Kt);
  k_chunkB<<<256, 256, 0, stream>>>(qkv2, Tbv, nTbk, Aq, Kt, vecs, oB);
  k_lng<<<16384, 256, 0, stream>>>(oB, pG, lnw, lnb, og);
  k_gemm<0><<<dim3(16, 32), 256, 0, stream>>>(og, Wot, out, nullptr, 2048);
}